// Round 1
// baseline (2236.444 us; speedup 1.0000x reference)
//
#include <hip/hip_runtime.h>
#include <hip/hip_bf16.h>
#include <math.h>

#define D 128

typedef __attribute__((ext_vector_type(4))) float f32x4;
typedef __attribute__((ext_vector_type(8))) short bf16x8;

__device__ inline unsigned short f2bf(float f){
  unsigned u = __float_as_uint(f);
  u += 0x7fffu + ((u >> 16) & 1u);
  return (unsigned short)(u >> 16);
}
__device__ inline float wred_sum(float v){
#pragma unroll
  for (int m = 1; m < 64; m <<= 1) v += __shfl_xor(v, m, 64);
  return v;
}
__device__ inline float wred_max(float v){
#pragma unroll
  for (int m = 1; m < 64; m <<= 1) v = fmaxf(v, __shfl_xor(v, m, 64));
  return v;
}

// ---- embedding mean-pool: wave per node ----
__global__ __launch_bounds__(256) void k_pool(const int* __restrict__ xpad,
    const float* __restrict__ emb, float* __restrict__ xo, int N, int M){
  int wv = threadIdx.x >> 6, ln = threadIdx.x & 63;
  int n = blockIdx.x * 4 + wv;
  if (n >= N) return;
  float2 acc = {0.f, 0.f}; int cnt = 0;
  for (int m = 0; m < M; ++m){
    int idx = xpad[n * M + m];
    if (idx >= 0){
      const float2* er = (const float2*)(emb + (size_t)idx * D);
      float2 v = er[ln];
      acc.x += v.x; acc.y += v.y; ++cnt;
    }
  }
  float inv = 1.f / (float)cnt;
  float2 o; o.x = acc.x * inv; o.y = acc.y * inv;
  ((float2*)(xo + (size_t)n * D))[ln] = o;
}

// ---- CSR build over buckets (dst*R + et) ----
__global__ void k_count(const int* __restrict__ dst, const int* __restrict__ et,
                        int* __restrict__ cnt, int E, int R){
  int e = blockIdx.x * 256 + threadIdx.x;
  if (e < E) atomicAdd(&cnt[dst[e] * R + et[e]], 1);
}

__global__ __launch_bounds__(1024) void k_scan(int* __restrict__ cc, int* __restrict__ rp, int nb){
  __shared__ int sh[1024];
  int t = threadIdx.x;
  int chunk = (nb + 1023) >> 10;
  int s = t * chunk, e = s + chunk;
  if (s > nb) s = nb;
  if (e > nb) e = nb;
  int sum = 0;
  for (int i = s; i < e; ++i) sum += cc[i];
  sh[t] = sum; __syncthreads();
  for (int off = 1; off < 1024; off <<= 1){
    int v = sh[t];
    int u = (t >= off) ? sh[t - off] : 0;
    __syncthreads();
    sh[t] = v + u;
    __syncthreads();
  }
  int run = (t > 0) ? sh[t - 1] : 0;
  int total = sh[1023];
  for (int i = s; i < e; ++i){
    int c = cc[i];
    rp[i] = run; cc[i] = run; run += c;
  }
  if (t == 1023) rp[nb] = total;
}

__global__ void k_scatter(const int* __restrict__ src, const int* __restrict__ dst,
    const int* __restrict__ et, int* __restrict__ cur, int* __restrict__ pack, int E, int R){
  int e = blockIdx.x * 256 + threadIdx.x;
  if (e < E){
    int t = et[e];
    int p = atomicAdd(&cur[dst[e] * R + t], 1);
    pack[p] = (t << 27) | src[e];
  }
}

// ---- wq[r][d] = sum_h w[r][d][h]*q[h]; wk likewise ----
__global__ void k_wqk(const float* __restrict__ w, const float* __restrict__ q,
    const float* __restrict__ kk, float* __restrict__ wq, float* __restrict__ wk, int RD){
  int id = blockIdx.x * 256 + threadIdx.x;
  if (id >= RD) return;
  const float* wr = w + (size_t)id * D;
  float sq = 0.f, sk = 0.f;
  for (int h = 0; h < D; ++h){ float v = wr[h]; sq += v * q[h]; sk += v * kk[h]; }
  wq[id] = sq; wk[id] = sk;
}

// ---- a[n,r]=x[n].wq[r], b[n,r]=x[n].wk[r]: wave per node ----
__global__ __launch_bounds__(256) void k_ab(const float* __restrict__ x,
    const float* __restrict__ wq, const float* __restrict__ wk,
    float* __restrict__ aT, float* __restrict__ bT, int N, int R){
  __shared__ float lq[8 * D], lk[8 * D];
  for (int i = threadIdx.x; i < R * D; i += 256){ lq[i] = wq[i]; lk[i] = wk[i]; }
  __syncthreads();
  int wv = threadIdx.x >> 6, ln = threadIdx.x & 63;
  int n = blockIdx.x * 4 + wv;
  if (n >= N) return;
  float2 xv = ((const float2*)(x + (size_t)n * D))[ln];
  for (int r = 0; r < R; ++r){
    float pa = xv.x * lq[r * D + 2 * ln] + xv.y * lq[r * D + 2 * ln + 1];
    float pb = xv.x * lk[r * D + 2 * ln] + xv.y * lk[r * D + 2 * ln + 1];
    pa = wred_sum(pa); pb = wred_sum(pb);
    if (ln == 0){ aT[n * R + r] = pa; bT[n * R + r] = pb; }
  }
}

// ---- segment softmax over dst: wave per node ----
__global__ __launch_bounds__(256) void k_alpha(const int* __restrict__ rp,
    const int* __restrict__ pack, const float* __restrict__ aT, const float* __restrict__ bT,
    float* __restrict__ alp, int N, int R){
  int wv = threadIdx.x >> 6, ln = threadIdx.x & 63;
  int n = blockIdx.x * 4 + wv;
  if (n >= N) return;
  int beg = rp[n * R], end = rp[n * R + R];
  if (end <= beg) return;
  float mx = -3.4e38f;
  for (int i = beg + ln; i < end; i += 64){
    int v = pack[i]; int t = v >> 27; int s = v & 0x7ffffff;
    float l = aT[n * R + t] + bT[s * R + t];
    l = l > 0.f ? l : 0.2f * l;
    mx = fmaxf(mx, l);
  }
  mx = wred_max(mx);
  float sm = 0.f;
  for (int i = beg + ln; i < end; i += 64){
    int v = pack[i]; int t = v >> 27; int s = v & 0x7ffffff;
    float l = aT[n * R + t] + bT[s * R + t];
    l = l > 0.f ? l : 0.2f * l;
    float ev = __expf(l - mx);
    alp[i] = ev; sm += ev;
  }
  sm = wred_sum(sm);
  float inv = 1.f / sm;
  for (int i = beg + ln; i < end; i += 64) alp[i] *= inv;
}

// ---- fused aggregate (S-tile in LDS) + MFMA GEMM vs w[r] + bias + relu ----
__global__ __launch_bounds__(256) void k_agg(const float* __restrict__ x_in,
    const float* __restrict__ w, const float* __restrict__ bias,
    const int* __restrict__ rp, const int* __restrict__ pack,
    const float* __restrict__ alp, float* __restrict__ x_out, int N, int R){
  __shared__ float st[64][132];          // S tile, padded
  __shared__ unsigned short wt[128][136]; // w[r] transposed [h][d], bf16, padded
  int wv = threadIdx.x >> 6, ln = threadIdx.x & 63;
  int g = ln >> 4, m16 = ln & 15;
  int n0 = blockIdx.x * 64;
  f32x4 acc[8];
#pragma unroll
  for (int i = 0; i < 8; ++i) acc[i] = (f32x4){0.f, 0.f, 0.f, 0.f};

  for (int r = 0; r < R; ++r){
    __syncthreads();   // previous iteration's LDS reads complete
    // load w[r] (fp32 [d][h]) -> wt[h][d] bf16
    for (int i = threadIdx.x; i < 128 * 128; i += 256){
      int d = i >> 7, h = i & 127;
      wt[h][d] = f2bf(w[((size_t)r * 128 + d) * 128 + h]);
    }
    // edge accumulation: wave owns rows [wv*16, wv*16+16)
    for (int j = 0; j < 16; ++j){
      int n = n0 + wv * 16 + j;
      float2 s2 = {0.f, 0.f};
      if (n < N){
        int beg = rp[n * R + r], end = rp[n * R + r + 1];
        for (int i = beg; i < end; ++i){
          int s = pack[i] & 0x7ffffff;
          float al = alp[i];
          float2 xv = ((const float2*)(x_in + (size_t)s * D))[ln];
          s2.x += al * xv.x; s2.y += al * xv.y;
        }
      }
      *(float2*)&st[wv * 16 + j][2 * ln] = s2;
    }
    __syncthreads();
    // MFMA: D[m][h] += S[m][k] * w[k][h]
#pragma unroll
    for (int kc = 0; kc < 4; ++kc){
      const float* ap = &st[wv * 16 + m16][kc * 32 + g * 8];
      float4 a0 = *(const float4*)ap;
      float4 a1 = *(const float4*)(ap + 4);
      bf16x8 af;
      af[0] = (short)f2bf(a0.x); af[1] = (short)f2bf(a0.y);
      af[2] = (short)f2bf(a0.z); af[3] = (short)f2bf(a0.w);
      af[4] = (short)f2bf(a1.x); af[5] = (short)f2bf(a1.y);
      af[6] = (short)f2bf(a1.z); af[7] = (short)f2bf(a1.w);
#pragma unroll
      for (int hf = 0; hf < 8; ++hf){
        bf16x8 bf = *(const bf16x8*)&wt[hf * 16 + m16][kc * 32 + g * 8];
        acc[hf] = __builtin_amdgcn_mfma_f32_16x16x32_bf16(af, bf, acc[hf], 0, 0, 0);
      }
    }
  }
  // epilogue: +bias, relu, store
#pragma unroll
  for (int hf = 0; hf < 8; ++hf){
    int h = hf * 16 + m16;
    float bv = bias[h];
#pragma unroll
    for (int jj = 0; jj < 4; ++jj){
      int n = n0 + wv * 16 + g * 4 + jj;
      if (n < N){
        float v = acc[hf][jj] + bv;
        x_out[(size_t)n * D + h] = fmaxf(v, 0.f);
      }
    }
  }
}

// ---- final linear + per-graph segment sum (atomic) ----
__global__ __launch_bounds__(256) void k_final(const float* __restrict__ x,
    const float* __restrict__ lw, const float* __restrict__ lb,
    const int* __restrict__ batch, float* __restrict__ out, int N){
  __shared__ unsigned short wt[128][136]; // lin_w [h][k] bf16
  for (int i = threadIdx.x; i < 128 * 128; i += 256){
    int h = i >> 7, k = i & 127;
    wt[h][k] = f2bf(lw[i]);
  }
  __syncthreads();
  int wv = threadIdx.x >> 6, ln = threadIdx.x & 63;
  int g = ln >> 4, m16 = ln & 15;
  int n0 = blockIdx.x * 64;
  f32x4 acc[8];
#pragma unroll
  for (int i = 0; i < 8; ++i) acc[i] = (f32x4){0.f, 0.f, 0.f, 0.f};
#pragma unroll
  for (int kc = 0; kc < 4; ++kc){
    int nA = n0 + wv * 16 + m16;
    float4 a0 = {0.f,0.f,0.f,0.f}, a1 = {0.f,0.f,0.f,0.f};
    if (nA < N){
      const float* ap = x + (size_t)nA * D + kc * 32 + g * 8;
      a0 = *(const float4*)ap; a1 = *(const float4*)(ap + 4);
    }
    bf16x8 af;
    af[0] = (short)f2bf(a0.x); af[1] = (short)f2bf(a0.y);
    af[2] = (short)f2bf(a0.z); af[3] = (short)f2bf(a0.w);
    af[4] = (short)f2bf(a1.x); af[5] = (short)f2bf(a1.y);
    af[6] = (short)f2bf(a1.z); af[7] = (short)f2bf(a1.w);
#pragma unroll
    for (int hf = 0; hf < 8; ++hf){
      bf16x8 bf = *(const bf16x8*)&wt[hf * 16 + m16][kc * 32 + g * 8];
      acc[hf] = __builtin_amdgcn_mfma_f32_16x16x32_bf16(af, bf, acc[hf], 0, 0, 0);
    }
  }
#pragma unroll
  for (int hf = 0; hf < 8; ++hf){
    int h = hf * 16 + m16;
    float bv = lb[h];
#pragma unroll
    for (int jj = 0; jj < 4; ++jj){
      int n = n0 + wv * 16 + g * 4 + jj;
      if (n < N){
        int bg = batch[n];
        atomicAdd(&out[(size_t)bg * D + h], acc[hf][jj] + bv);
      }
    }
  }
}

extern "C" void kernel_launch(void* const* d_in, const int* in_sizes, int n_in,
                              void* d_out, int out_size, void* d_ws, size_t ws_size,
                              hipStream_t stream){
  const int*   xpad  = (const int*)d_in[0];
  const int*   eidx  = (const int*)d_in[1];
  const int*   etyp  = (const int*)d_in[2];
  const int*   batch = (const int*)d_in[3];
  const float* emb   = (const float*)d_in[4];
  const float* w1    = (const float*)d_in[5];
  const float* q1    = (const float*)d_in[6];
  const float* k1    = (const float*)d_in[7];
  const float* b1    = (const float*)d_in[8];
  const float* w2    = (const float*)d_in[9];
  const float* q2    = (const float*)d_in[10];
  const float* k2    = (const float*)d_in[11];
  const float* b2    = (const float*)d_in[12];
  const float* lw    = (const float*)d_in[13];
  const float* lb    = (const float*)d_in[14];

  int N = in_sizes[3];
  int M = in_sizes[0] / N;
  int E = in_sizes[2];
  int R = in_sizes[5] / (128 * 128);
  int NB = N * R;
  const int* esrc = eidx;
  const int* edst = eidx + E;

  char* p = (char*)d_ws;
  auto carve = [&](size_t b) -> void* {
    void* q = (void*)p; p += (b + 255) & ~(size_t)255; return q;
  };
  float* x_a  = (float*)carve((size_t)N * D * 4);
  float* x_b  = (float*)carve((size_t)N * D * 4);
  float* wq1  = (float*)carve((size_t)R * D * 4);
  float* wk1  = (float*)carve((size_t)R * D * 4);
  float* wq2  = (float*)carve((size_t)R * D * 4);
  float* wk2  = (float*)carve((size_t)R * D * 4);
  float* aT   = (float*)carve((size_t)N * R * 4);
  float* bT   = (float*)carve((size_t)N * R * 4);
  int*   rp   = (int*)carve((size_t)(NB + 1) * 4);
  int*   cur  = (int*)carve((size_t)NB * 4);
  int*   pack = (int*)carve((size_t)E * 4);
  float* alp  = (float*)carve((size_t)E * 4);
  if ((size_t)(p - (char*)d_ws) > ws_size) return;  // ws too small: fail visibly

  hipMemsetAsync(cur, 0, (size_t)NB * 4, stream);
  hipMemsetAsync(d_out, 0, (size_t)out_size * 4, stream);

  int eg = (E + 255) / 256;
  k_count  <<<eg, 256, 0, stream>>>(edst, etyp, cur, E, R);
  k_scan   <<<1, 1024, 0, stream>>>(cur, rp, NB);
  k_scatter<<<eg, 256, 0, stream>>>(esrc, edst, etyp, cur, pack, E, R);

  k_wqk<<<(R * D + 255) / 256, 256, 0, stream>>>(w1, q1, k1, wq1, wk1, R * D);
  k_wqk<<<(R * D + 255) / 256, 256, 0, stream>>>(w2, q2, k2, wq2, wk2, R * D);

  int ng4 = (N + 3) / 4;
  int ntile = (N + 63) / 64;
  k_pool<<<ng4, 256, 0, stream>>>(xpad, emb, x_a, N, M);

  // layer 1
  k_ab   <<<ng4, 256, 0, stream>>>(x_a, wq1, wk1, aT, bT, N, R);
  k_alpha<<<ng4, 256, 0, stream>>>(rp, pack, aT, bT, alp, N, R);
  k_agg  <<<ntile, 256, 0, stream>>>(x_a, w1, b1, rp, pack, alp, x_b, N, R);

  // layer 2
  k_ab   <<<ng4, 256, 0, stream>>>(x_b, wq2, wk2, aT, bT, N, R);
  k_alpha<<<ng4, 256, 0, stream>>>(rp, pack, aT, bT, alp, N, R);
  k_agg  <<<ntile, 256, 0, stream>>>(x_b, w2, b2, rp, pack, alp, x_a, N, R);

  // final linear + graph segment-sum
  k_final<<<ntile, 256, 0, stream>>>(x_a, lw, lb, batch, (float*)d_out, N);
}

// Round 2
// 1299.031 us; speedup vs baseline: 1.7216x; 1.7216x over previous
//
#include <hip/hip_runtime.h>
#include <hip/hip_bf16.h>
#include <math.h>

#define D 128

typedef __attribute__((ext_vector_type(4))) float f32x4;
typedef __attribute__((ext_vector_type(8))) short bf16x8;

__device__ inline unsigned short f2bf(float f){
  unsigned u = __float_as_uint(f);
  u += 0x7fffu + ((u >> 16) & 1u);
  return (unsigned short)(u >> 16);
}
__device__ inline float wred_sum(float v){
#pragma unroll
  for (int m = 1; m < 64; m <<= 1) v += __shfl_xor(v, m, 64);
  return v;
}
__device__ inline float wred_max(float v){
#pragma unroll
  for (int m = 1; m < 64; m <<= 1) v = fmaxf(v, __shfl_xor(v, m, 64));
  return v;
}

// ---- embedding mean-pool: wave per node ----
__global__ __launch_bounds__(256) void k_pool(const int* __restrict__ xpad,
    const float* __restrict__ emb, float* __restrict__ xo, int N, int M){
  int wv = threadIdx.x >> 6, ln = threadIdx.x & 63;
  int n = blockIdx.x * 4 + wv;
  if (n >= N) return;
  float2 acc = {0.f, 0.f}; int cnt = 0;
  for (int m = 0; m < M; ++m){
    int idx = xpad[n * M + m];
    if (idx >= 0){
      const float2* er = (const float2*)(emb + (size_t)idx * D);
      float2 v = er[ln];
      acc.x += v.x; acc.y += v.y; ++cnt;
    }
  }
  float inv = 1.f / (float)cnt;
  float2 o; o.x = acc.x * inv; o.y = acc.y * inv;
  ((float2*)(xo + (size_t)n * D))[ln] = o;
}

// ---- CSR build over buckets (dst*R + et) ----
__global__ void k_count(const int* __restrict__ dst, const int* __restrict__ et,
                        int* __restrict__ cnt, int E, int R){
  int e = blockIdx.x * 256 + threadIdx.x;
  if (e < E) atomicAdd(&cnt[dst[e] * R + et[e]], 1);
}

// ---- hierarchical exclusive scan over nb buckets (1024 elems / block) ----
__global__ __launch_bounds__(256) void k_scan_blk(const int* __restrict__ cc,
    int* __restrict__ bsum, int nb){
  __shared__ int sh[256];
  int base = blockIdx.x * 1024 + threadIdx.x * 4;
  int s = 0;
#pragma unroll
  for (int j = 0; j < 4; ++j){
    int i = base + j;
    if (i < nb) s += cc[i];
  }
  sh[threadIdx.x] = s; __syncthreads();
  for (int off = 128; off > 0; off >>= 1){
    if (threadIdx.x < off) sh[threadIdx.x] += sh[threadIdx.x + off];
    __syncthreads();
  }
  if (threadIdx.x == 0) bsum[blockIdx.x] = sh[0];
}

__global__ __launch_bounds__(1024) void k_scan_top(const int* __restrict__ bsum,
    int* __restrict__ boff, int* __restrict__ rp, int nblk, int nb){
  __shared__ int sh[1024];
  int t = threadIdx.x;
  int v = (t < nblk) ? bsum[t] : 0;
  sh[t] = v; __syncthreads();
  for (int off = 1; off < 1024; off <<= 1){
    int a = sh[t];
    int b = (t >= off) ? sh[t - off] : 0;
    __syncthreads();
    sh[t] = a + b;
    __syncthreads();
  }
  if (t < nblk) boff[t] = sh[t] - v;       // exclusive
  if (t == 1023) rp[nb] = sh[1023];        // total
}

__global__ __launch_bounds__(256) void k_scan_fin(int* __restrict__ cc,
    const int* __restrict__ boff, int* __restrict__ rp, int nb){
  __shared__ int sh[256];
  int t = threadIdx.x;
  int base = blockIdx.x * 1024 + t * 4;
  int c[4]; int local = 0;
#pragma unroll
  for (int j = 0; j < 4; ++j){
    int i = base + j;
    c[j] = (i < nb) ? cc[i] : 0;
    local += c[j];
  }
  sh[t] = local; __syncthreads();
  for (int off = 1; off < 256; off <<= 1){
    int a = sh[t];
    int b = (t >= off) ? sh[t - off] : 0;
    __syncthreads();
    sh[t] = a + b;
    __syncthreads();
  }
  int run = sh[t] - local + boff[blockIdx.x];
#pragma unroll
  for (int j = 0; j < 4; ++j){
    int i = base + j;
    if (i < nb){ rp[i] = run; cc[i] = run; run += c[j]; }
  }
}

__global__ void k_scatter(const int* __restrict__ src, const int* __restrict__ dst,
    const int* __restrict__ et, int* __restrict__ cur, int* __restrict__ pack, int E, int R){
  int e = blockIdx.x * 256 + threadIdx.x;
  if (e < E){
    int t = et[e];
    int p = atomicAdd(&cur[dst[e] * R + t], 1);
    pack[p] = (t << 27) | src[e];
  }
}

// ---- wq[r][d] = sum_h w[r][d][h]*q[h]; wk likewise ----
__global__ void k_wqk(const float* __restrict__ w, const float* __restrict__ q,
    const float* __restrict__ kk, float* __restrict__ wq, float* __restrict__ wk, int RD){
  int id = blockIdx.x * 256 + threadIdx.x;
  if (id >= RD) return;
  const float* wr = w + (size_t)id * D;
  float sq = 0.f, sk = 0.f;
  for (int h = 0; h < D; ++h){ float v = wr[h]; sq += v * q[h]; sk += v * kk[h]; }
  wq[id] = sq; wk[id] = sk;
}

// ---- w[r][d][h] fp32 -> wbf[r][h][d] bf16 (transposed) ----
__global__ void k_wtr(const float* __restrict__ w, unsigned short* __restrict__ wbf, int total){
  int id = blockIdx.x * 256 + threadIdx.x;
  if (id >= total) return;
  int d = id & 127, h = (id >> 7) & 127, r = id >> 14;
  wbf[id] = f2bf(w[(size_t)r * 16384 + d * 128 + h]);
}

// ---- plain fp32 -> bf16 convert (no transpose) ----
__global__ void k_cvt(const float* __restrict__ s, unsigned short* __restrict__ dd, int total){
  int id = blockIdx.x * 256 + threadIdx.x;
  if (id < total) dd[id] = f2bf(s[id]);
}

// ---- a[n,r]=x[n].wq[r], b[n,r]=x[n].wk[r]: wave per node ----
__global__ __launch_bounds__(256) void k_ab(const float* __restrict__ x,
    const float* __restrict__ wq, const float* __restrict__ wk,
    float* __restrict__ aT, float* __restrict__ bT, int N, int R){
  __shared__ float lq[8 * D], lk[8 * D];
  for (int i = threadIdx.x; i < R * D; i += 256){ lq[i] = wq[i]; lk[i] = wk[i]; }
  __syncthreads();
  int wv = threadIdx.x >> 6, ln = threadIdx.x & 63;
  int n = blockIdx.x * 4 + wv;
  if (n >= N) return;
  float2 xv = ((const float2*)(x + (size_t)n * D))[ln];
  for (int r = 0; r < R; ++r){
    float pa = xv.x * lq[r * D + 2 * ln] + xv.y * lq[r * D + 2 * ln + 1];
    float pb = xv.x * lk[r * D + 2 * ln] + xv.y * lk[r * D + 2 * ln + 1];
    pa = wred_sum(pa); pb = wred_sum(pb);
    if (ln == 0){ aT[n * R + r] = pa; bT[n * R + r] = pb; }
  }
}

// ---- segment softmax over dst: wave per node ----
__global__ __launch_bounds__(256) void k_alpha(const int* __restrict__ rp,
    const int* __restrict__ pack, const float* __restrict__ aT, const float* __restrict__ bT,
    float* __restrict__ alp, int N, int R){
  int wv = threadIdx.x >> 6, ln = threadIdx.x & 63;
  int n = blockIdx.x * 4 + wv;
  if (n >= N) return;
  int beg = rp[n * R], end = rp[n * R + R];
  if (end <= beg) return;
  float mx = -3.4e38f;
  for (int i = beg + ln; i < end; i += 64){
    int v = pack[i]; int t = v >> 27; int s = v & 0x7ffffff;
    float l = aT[n * R + t] + bT[s * R + t];
    l = l > 0.f ? l : 0.2f * l;
    mx = fmaxf(mx, l);
  }
  mx = wred_max(mx);
  float sm = 0.f;
  for (int i = beg + ln; i < end; i += 64){
    int v = pack[i]; int t = v >> 27; int s = v & 0x7ffffff;
    float l = aT[n * R + t] + bT[s * R + t];
    l = l > 0.f ? l : 0.2f * l;
    float ev = __expf(l - mx);
    alp[i] = ev; sm += ev;
  }
  sm = wred_sum(sm);
  float inv = 1.f / sm;
  for (int i = beg + ln; i < end; i += 64) alp[i] *= inv;
}

// ---- fused aggregate (S-tile in LDS) + MFMA GEMM vs w[r] + bias + relu ----
__global__ __launch_bounds__(256) void k_agg(const float* __restrict__ x_in,
    const unsigned short* __restrict__ wbf, const float* __restrict__ bias,
    const int* __restrict__ rp, const int* __restrict__ pack,
    const float* __restrict__ alp, float* __restrict__ x_out, int N, int R){
  __shared__ float st[64][132];           // S tile, padded
  __shared__ unsigned short wt[128][136]; // w[r] transposed [h][d], bf16 (136*2=272B rows, 16B aligned)
  int wv = threadIdx.x >> 6, ln = threadIdx.x & 63;
  int g = ln >> 4, m16 = ln & 15;
  int n0 = blockIdx.x * 64;
  f32x4 acc[8];
#pragma unroll
  for (int i = 0; i < 8; ++i) acc[i] = (f32x4){0.f, 0.f, 0.f, 0.f};

  for (int r = 0; r < R; ++r){
    __syncthreads();   // previous iteration's LDS reads complete
    // stage wbf[r] ([h][d] bf16) -> wt via 16B copies
    {
      const uint4* src = (const uint4*)(wbf + (size_t)r * 16384);
      for (int i = threadIdx.x; i < 2048; i += 256){
        int h = i >> 4, dblk = i & 15;
        *(uint4*)&wt[h][dblk * 8] = src[i];
      }
    }
    // edge accumulation: wave owns rows [wv*16, wv*16+16)
    for (int j = 0; j < 16; ++j){
      int n = n0 + wv * 16 + j;
      float2 s2 = {0.f, 0.f};
      if (n < N){
        int beg = rp[n * R + r], end = rp[n * R + r + 1];
        for (int i = beg; i < end; ++i){
          int s = pack[i] & 0x7ffffff;
          float al = alp[i];
          float2 xv = ((const float2*)(x_in + (size_t)s * D))[ln];
          s2.x += al * xv.x; s2.y += al * xv.y;
        }
      }
      *(float2*)&st[wv * 16 + j][2 * ln] = s2;
    }
    __syncthreads();
    // MFMA: D[m][h] += S[m][k] * w[k][h]
#pragma unroll
    for (int kc = 0; kc < 4; ++kc){
      const float* ap = &st[wv * 16 + m16][kc * 32 + g * 8];
      float4 a0 = *(const float4*)ap;
      float4 a1 = *(const float4*)(ap + 4);
      bf16x8 af;
      af[0] = (short)f2bf(a0.x); af[1] = (short)f2bf(a0.y);
      af[2] = (short)f2bf(a0.z); af[3] = (short)f2bf(a0.w);
      af[4] = (short)f2bf(a1.x); af[5] = (short)f2bf(a1.y);
      af[6] = (short)f2bf(a1.z); af[7] = (short)f2bf(a1.w);
#pragma unroll
      for (int hf = 0; hf < 8; ++hf){
        bf16x8 bf = *(const bf16x8*)&wt[hf * 16 + m16][kc * 32 + g * 8];
        acc[hf] = __builtin_amdgcn_mfma_f32_16x16x32_bf16(af, bf, acc[hf], 0, 0, 0);
      }
    }
  }
  // epilogue: +bias, relu, store
#pragma unroll
  for (int hf = 0; hf < 8; ++hf){
    int h = hf * 16 + m16;
    float bv = bias[h];
#pragma unroll
    for (int jj = 0; jj < 4; ++jj){
      int n = n0 + wv * 16 + g * 4 + jj;
      if (n < N){
        float v = acc[hf][jj] + bv;
        x_out[(size_t)n * D + h] = fmaxf(v, 0.f);
      }
    }
  }
}

// ---- final linear + per-graph segment sum (atomic) ----
__global__ __launch_bounds__(256) void k_final(const float* __restrict__ x,
    const unsigned short* __restrict__ lwbf, const float* __restrict__ lb,
    const int* __restrict__ batch, float* __restrict__ out, int N){
  __shared__ unsigned short wt[128][136]; // lin_w [h][k] bf16
  {
    const uint4* src = (const uint4*)lwbf;
    for (int i = threadIdx.x; i < 2048; i += 256){
      int h = i >> 4, kblk = i & 15;
      *(uint4*)&wt[h][kblk * 8] = src[i];
    }
  }
  __syncthreads();
  int wv = threadIdx.x >> 6, ln = threadIdx.x & 63;
  int g = ln >> 4, m16 = ln & 15;
  int n0 = blockIdx.x * 64;
  f32x4 acc[8];
#pragma unroll
  for (int i = 0; i < 8; ++i) acc[i] = (f32x4){0.f, 0.f, 0.f, 0.f};
#pragma unroll
  for (int kc = 0; kc < 4; ++kc){
    int nA = n0 + wv * 16 + m16;
    float4 a0 = {0.f,0.f,0.f,0.f}, a1 = {0.f,0.f,0.f,0.f};
    if (nA < N){
      const float* ap = x + (size_t)nA * D + kc * 32 + g * 8;
      a0 = *(const float4*)ap; a1 = *(const float4*)(ap + 4);
    }
    bf16x8 af;
    af[0] = (short)f2bf(a0.x); af[1] = (short)f2bf(a0.y);
    af[2] = (short)f2bf(a0.z); af[3] = (short)f2bf(a0.w);
    af[4] = (short)f2bf(a1.x); af[5] = (short)f2bf(a1.y);
    af[6] = (short)f2bf(a1.z); af[7] = (short)f2bf(a1.w);
#pragma unroll
    for (int hf = 0; hf < 8; ++hf){
      bf16x8 bf = *(const bf16x8*)&wt[hf * 16 + m16][kc * 32 + g * 8];
      acc[hf] = __builtin_amdgcn_mfma_f32_16x16x32_bf16(af, bf, acc[hf], 0, 0, 0);
    }
  }
#pragma unroll
  for (int hf = 0; hf < 8; ++hf){
    int h = hf * 16 + m16;
    float bv = lb[h];
#pragma unroll
    for (int jj = 0; jj < 4; ++jj){
      int n = n0 + wv * 16 + g * 4 + jj;
      if (n < N){
        int bg = batch[n];
        atomicAdd(&out[(size_t)bg * D + h], acc[hf][jj] + bv);
      }
    }
  }
}

extern "C" void kernel_launch(void* const* d_in, const int* in_sizes, int n_in,
                              void* d_out, int out_size, void* d_ws, size_t ws_size,
                              hipStream_t stream){
  const int*   xpad  = (const int*)d_in[0];
  const int*   eidx  = (const int*)d_in[1];
  const int*   etyp  = (const int*)d_in[2];
  const int*   batch = (const int*)d_in[3];
  const float* emb   = (const float*)d_in[4];
  const float* w1    = (const float*)d_in[5];
  const float* q1    = (const float*)d_in[6];
  const float* k1    = (const float*)d_in[7];
  const float* b1    = (const float*)d_in[8];
  const float* w2    = (const float*)d_in[9];
  const float* q2    = (const float*)d_in[10];
  const float* k2    = (const float*)d_in[11];
  const float* b2    = (const float*)d_in[12];
  const float* lw    = (const float*)d_in[13];
  const float* lb    = (const float*)d_in[14];

  int N = in_sizes[3];
  int M = in_sizes[0] / N;
  int E = in_sizes[2];
  int R = in_sizes[5] / (128 * 128);
  int NB = N * R;
  const int* esrc = eidx;
  const int* edst = eidx + E;

  char* p = (char*)d_ws;
  auto carve = [&](size_t b) -> void* {
    void* q = (void*)p; p += (b + 255) & ~(size_t)255; return q;
  };
  float* x_a  = (float*)carve((size_t)N * D * 4);
  float* x_b  = (float*)carve((size_t)N * D * 4);
  float* wq1  = (float*)carve((size_t)R * D * 4);
  float* wk1  = (float*)carve((size_t)R * D * 4);
  float* wq2  = (float*)carve((size_t)R * D * 4);
  float* wk2  = (float*)carve((size_t)R * D * 4);
  float* aT   = (float*)carve((size_t)N * R * 4);
  float* bT   = (float*)carve((size_t)N * R * 4);
  int*   rp   = (int*)carve((size_t)(NB + 1) * 4);
  int*   cur  = (int*)carve((size_t)NB * 4);
  int*   pack = (int*)carve((size_t)E * 4);
  float* alp  = (float*)carve((size_t)E * 4);
  unsigned short* wbf1 = (unsigned short*)carve((size_t)R * 128 * 128 * 2);
  unsigned short* wbf2 = (unsigned short*)carve((size_t)R * 128 * 128 * 2);
  unsigned short* lwbf = (unsigned short*)carve((size_t)128 * 128 * 2);
  int* bsum = (int*)carve((size_t)4096 * 4);
  int* boff = (int*)carve((size_t)4096 * 4);
  if ((size_t)(p - (char*)d_ws) > ws_size) return;  // ws too small: fail visibly

  hipMemsetAsync(cur, 0, (size_t)NB * 4, stream);
  hipMemsetAsync(d_out, 0, (size_t)out_size * 4, stream);

  int eg = (E + 255) / 256;
  int nblk = (NB + 1023) / 1024;
  k_count   <<<eg, 256, 0, stream>>>(edst, etyp, cur, E, R);
  k_scan_blk<<<nblk, 256, 0, stream>>>(cur, bsum, NB);
  k_scan_top<<<1, 1024, 0, stream>>>(bsum, boff, rp, nblk, NB);
  k_scan_fin<<<nblk, 256, 0, stream>>>(cur, boff, rp, NB);
  k_scatter <<<eg, 256, 0, stream>>>(esrc, edst, etyp, cur, pack, E, R);

  k_wqk<<<(R * D + 255) / 256, 256, 0, stream>>>(w1, q1, k1, wq1, wk1, R * D);
  k_wqk<<<(R * D + 255) / 256, 256, 0, stream>>>(w2, q2, k2, wq2, wk2, R * D);
  int wtot = R * 128 * 128;
  k_wtr<<<(wtot + 255) / 256, 256, 0, stream>>>(w1, wbf1, wtot);
  k_wtr<<<(wtot + 255) / 256, 256, 0, stream>>>(w2, wbf2, wtot);
  k_cvt<<<(128 * 128 + 255) / 256, 256, 0, stream>>>(lw, lwbf, 128 * 128);

  int ng4 = (N + 3) / 4;
  int ntile = (N + 63) / 64;
  k_pool<<<ng4, 256, 0, stream>>>(xpad, emb, x_a, N, M);

  // layer 1
  k_ab   <<<ng4, 256, 0, stream>>>(x_a, wq1, wk1, aT, bT, N, R);
  k_alpha<<<ng4, 256, 0, stream>>>(rp, pack, aT, bT, alp, N, R);
  k_agg  <<<ntile, 256, 0, stream>>>(x_a, wbf1, b1, rp, pack, alp, x_b, N, R);

  // layer 2
  k_ab   <<<ng4, 256, 0, stream>>>(x_b, wq2, wk2, aT, bT, N, R);
  k_alpha<<<ng4, 256, 0, stream>>>(rp, pack, aT, bT, alp, N, R);
  k_agg  <<<ntile, 256, 0, stream>>>(x_b, wbf2, b2, rp, pack, alp, x_a, N, R);

  // final linear + graph segment-sum
  k_final<<<ntile, 256, 0, stream>>>(x_a, lwbf, lb, batch, (float*)d_out, N);
}

// Round 3
// 855.765 us; speedup vs baseline: 2.6134x; 1.5180x over previous
//
#include <hip/hip_runtime.h>
#include <hip/hip_bf16.h>
#include <math.h>

#define D 128

typedef __attribute__((ext_vector_type(4))) float f32x4;
typedef __attribute__((ext_vector_type(8))) short bf16x8;

__device__ inline unsigned short f2bf(float f){
  unsigned u = __float_as_uint(f);
  u += 0x7fffu + ((u >> 16) & 1u);
  return (unsigned short)(u >> 16);
}
__device__ inline float bf2f(unsigned short u){
  return __uint_as_float((unsigned)u << 16);
}
__device__ inline float wred_sum(float v){
#pragma unroll
  for (int m = 1; m < 64; m <<= 1) v += __shfl_xor(v, m, 64);
  return v;
}
__device__ inline float wred_max(float v){
#pragma unroll
  for (int m = 1; m < 64; m <<= 1) v = fmaxf(v, __shfl_xor(v, m, 64));
  return v;
}

// ---- embedding mean-pool: wave per node ----
__global__ __launch_bounds__(256) void k_pool(const int* __restrict__ xpad,
    const float* __restrict__ emb, float* __restrict__ xo, int N, int M){
  int wv = threadIdx.x >> 6, ln = threadIdx.x & 63;
  int n = blockIdx.x * 4 + wv;
  if (n >= N) return;
  float2 acc = {0.f, 0.f}; int cnt = 0;
  for (int m = 0; m < M; ++m){
    int idx = xpad[n * M + m];
    if (idx >= 0){
      const float2* er = (const float2*)(emb + (size_t)idx * D);
      float2 v = er[ln];
      acc.x += v.x; acc.y += v.y; ++cnt;
    }
  }
  float inv = 1.f / (float)cnt;
  float2 o; o.x = acc.x * inv; o.y = acc.y * inv;
  ((float2*)(xo + (size_t)n * D))[ln] = o;
}

// ---- CSR build over buckets (dst*R + et) ----
__global__ void k_count(const int* __restrict__ dst, const int* __restrict__ et,
                        int* __restrict__ cnt, int E, int R){
  int e = blockIdx.x * 256 + threadIdx.x;
  if (e < E) atomicAdd(&cnt[dst[e] * R + et[e]], 1);
}

// ---- hierarchical exclusive scan over nb buckets (1024 elems / block) ----
__global__ __launch_bounds__(256) void k_scan_blk(const int* __restrict__ cc,
    int* __restrict__ bsum, int nb){
  __shared__ int sh[256];
  int base = blockIdx.x * 1024 + threadIdx.x * 4;
  int s = 0;
#pragma unroll
  for (int j = 0; j < 4; ++j){
    int i = base + j;
    if (i < nb) s += cc[i];
  }
  sh[threadIdx.x] = s; __syncthreads();
  for (int off = 128; off > 0; off >>= 1){
    if (threadIdx.x < off) sh[threadIdx.x] += sh[threadIdx.x + off];
    __syncthreads();
  }
  if (threadIdx.x == 0) bsum[blockIdx.x] = sh[0];
}

__global__ __launch_bounds__(1024) void k_scan_top(const int* __restrict__ bsum,
    int* __restrict__ boff, int* __restrict__ rp, int nblk, int nb){
  __shared__ int sh[1024];
  int t = threadIdx.x;
  int v = (t < nblk) ? bsum[t] : 0;
  sh[t] = v; __syncthreads();
  for (int off = 1; off < 1024; off <<= 1){
    int a = sh[t];
    int b = (t >= off) ? sh[t - off] : 0;
    __syncthreads();
    sh[t] = a + b;
    __syncthreads();
  }
  if (t < nblk) boff[t] = sh[t] - v;       // exclusive
  if (t == 1023) rp[nb] = sh[1023];        // total
}

__global__ __launch_bounds__(256) void k_scan_fin(int* __restrict__ cc,
    const int* __restrict__ boff, int* __restrict__ rp, int nb){
  __shared__ int sh[256];
  int t = threadIdx.x;
  int base = blockIdx.x * 1024 + t * 4;
  int c[4]; int local = 0;
#pragma unroll
  for (int j = 0; j < 4; ++j){
    int i = base + j;
    c[j] = (i < nb) ? cc[i] : 0;
    local += c[j];
  }
  sh[t] = local; __syncthreads();
  for (int off = 1; off < 256; off <<= 1){
    int a = sh[t];
    int b = (t >= off) ? sh[t - off] : 0;
    __syncthreads();
    sh[t] = a + b;
    __syncthreads();
  }
  int run = sh[t] - local + boff[blockIdx.x];
#pragma unroll
  for (int j = 0; j < 4; ++j){
    int i = base + j;
    if (i < nb){ rp[i] = run; cc[i] = run; run += c[j]; }
  }
}

__global__ void k_scatter(const int* __restrict__ src, const int* __restrict__ dst,
    const int* __restrict__ et, int* __restrict__ cur, int* __restrict__ pack, int E, int R){
  int e = blockIdx.x * 256 + threadIdx.x;
  if (e < E){
    int t = et[e];
    int p = atomicAdd(&cur[dst[e] * R + t], 1);
    pack[p] = (t << 27) | src[e];
  }
}

// ---- wq[r][d] = sum_h w[r][d][h]*q[h]; wk likewise ----
__global__ void k_wqk(const float* __restrict__ w, const float* __restrict__ q,
    const float* __restrict__ kk, float* __restrict__ wq, float* __restrict__ wk, int RD){
  int id = blockIdx.x * 256 + threadIdx.x;
  if (id >= RD) return;
  const float* wr = w + (size_t)id * D;
  float sq = 0.f, sk = 0.f;
  for (int h = 0; h < D; ++h){ float v = wr[h]; sq += v * q[h]; sk += v * kk[h]; }
  wq[id] = sq; wk[id] = sk;
}

// ---- w[r][d][h] fp32 -> wbf[r][h][d] bf16 (transposed) ----
__global__ void k_wtr(const float* __restrict__ w, unsigned short* __restrict__ wbf, int total){
  int id = blockIdx.x * 256 + threadIdx.x;
  if (id >= total) return;
  int d = id & 127, h = (id >> 7) & 127, r = id >> 14;
  wbf[id] = f2bf(w[(size_t)r * 16384 + d * 128 + h]);
}

// ---- plain fp32 -> bf16 convert (no transpose) ----
__global__ void k_cvt(const float* __restrict__ s, unsigned short* __restrict__ dd, int total){
  int id = blockIdx.x * 256 + threadIdx.x;
  if (id < total) dd[id] = f2bf(s[id]);
}

// ---- a[n,r]=x[n].wq[r], b[n,r]=x[n].wk[r]: wave per node ----
__global__ __launch_bounds__(256) void k_ab(const float* __restrict__ x,
    const float* __restrict__ wq, const float* __restrict__ wk,
    float* __restrict__ aT, float* __restrict__ bT, int N, int R){
  __shared__ float lq[8 * D], lk[8 * D];
  for (int i = threadIdx.x; i < R * D; i += 256){ lq[i] = wq[i]; lk[i] = wk[i]; }
  __syncthreads();
  int wv = threadIdx.x >> 6, ln = threadIdx.x & 63;
  int n = blockIdx.x * 4 + wv;
  if (n >= N) return;
  float2 xv = ((const float2*)(x + (size_t)n * D))[ln];
  for (int r = 0; r < R; ++r){
    float pa = xv.x * lq[r * D + 2 * ln] + xv.y * lq[r * D + 2 * ln + 1];
    float pb = xv.x * lk[r * D + 2 * ln] + xv.y * lk[r * D + 2 * ln + 1];
    pa = wred_sum(pa); pb = wred_sum(pb);
    if (ln == 0){ aT[n * R + r] = pa; bT[n * R + r] = pb; }
  }
}

// ---- segment softmax over dst: wave per node ----
__global__ __launch_bounds__(256) void k_alpha(const int* __restrict__ rp,
    const int* __restrict__ pack, const float* __restrict__ aT, const float* __restrict__ bT,
    float* __restrict__ alp, int N, int R){
  int wv = threadIdx.x >> 6, ln = threadIdx.x & 63;
  int n = blockIdx.x * 4 + wv;
  if (n >= N) return;
  int beg = rp[n * R], end = rp[n * R + R];
  if (end <= beg) return;
  float mx = -3.4e38f;
  for (int i = beg + ln; i < end; i += 64){
    int v = pack[i]; int t = v >> 27; int s = v & 0x7ffffff;
    float l = aT[n * R + t] + bT[s * R + t];
    l = l > 0.f ? l : 0.2f * l;
    mx = fmaxf(mx, l);
  }
  mx = wred_max(mx);
  float sm = 0.f;
  for (int i = beg + ln; i < end; i += 64){
    int v = pack[i]; int t = v >> 27; int s = v & 0x7ffffff;
    float l = aT[n * R + t] + bT[s * R + t];
    l = l > 0.f ? l : 0.2f * l;
    float ev = __expf(l - mx);
    alp[i] = ev; sm += ev;
  }
  sm = wred_sum(sm);
  float inv = 1.f / sm;
  for (int i = beg + ln; i < end; i += 64) alp[i] *= inv;
}

// ---- xw[n][r*128+h] = (x[n] @ w[r])[h], bf16, via MFMA; B read from L1/L2 ----
__global__ __launch_bounds__(256) void k_xw(const float* __restrict__ x,
    const unsigned short* __restrict__ wbf,  // [R][h][k] bf16
    unsigned short* __restrict__ xw,         // [N][R*128] bf16
    int N, int R){
  int wv = threadIdx.x >> 6, ln = threadIdx.x & 63;
  int g = ln >> 4, m16 = ln & 15;
  int n0 = blockIdx.x * 64;
  int nA = n0 + wv * 16 + m16;
  bf16x8 af[4];
#pragma unroll
  for (int kc = 0; kc < 4; ++kc){
    float4 a0 = {0.f,0.f,0.f,0.f}, a1 = {0.f,0.f,0.f,0.f};
    if (nA < N){
      const float* ap = x + (size_t)nA * D + kc * 32 + g * 8;
      a0 = *(const float4*)ap; a1 = *(const float4*)(ap + 4);
    }
    af[kc][0] = (short)f2bf(a0.x); af[kc][1] = (short)f2bf(a0.y);
    af[kc][2] = (short)f2bf(a0.z); af[kc][3] = (short)f2bf(a0.w);
    af[kc][4] = (short)f2bf(a1.x); af[kc][5] = (short)f2bf(a1.y);
    af[kc][6] = (short)f2bf(a1.z); af[kc][7] = (short)f2bf(a1.w);
  }
  int RD128 = R * 128;
  for (int r = 0; r < R; ++r){
    f32x4 acc[8];
#pragma unroll
    for (int i = 0; i < 8; ++i) acc[i] = (f32x4){0.f, 0.f, 0.f, 0.f};
    const unsigned short* wr = wbf + (size_t)r * 16384;
#pragma unroll
    for (int kc = 0; kc < 4; ++kc){
#pragma unroll
      for (int hf = 0; hf < 8; ++hf){
        bf16x8 bfr = *(const bf16x8*)(wr + (hf * 16 + m16) * 128 + kc * 32 + g * 8);
        acc[hf] = __builtin_amdgcn_mfma_f32_16x16x32_bf16(af[kc], bfr, acc[hf], 0, 0, 0);
      }
    }
#pragma unroll
    for (int hf = 0; hf < 8; ++hf){
#pragma unroll
      for (int jj = 0; jj < 4; ++jj){
        int n = n0 + wv * 16 + g * 4 + jj;
        if (n < N) xw[(size_t)n * RD128 + r * 128 + hf * 16 + m16] = f2bf(acc[hf][jj]);
      }
    }
  }
}

// ---- aggregation: one wave per node, flat edge range, gather xw rows ----
__global__ __launch_bounds__(256) void k_aggX(const unsigned short* __restrict__ xw,
    const int* __restrict__ rp, const int* __restrict__ pack, const float* __restrict__ alp,
    const float* __restrict__ bias, float* __restrict__ xo, int N, int R){
  int wv = threadIdx.x >> 6, ln = threadIdx.x & 63;
  int n = blockIdx.x * 4 + wv;
  if (n >= N) return;
  int beg = rp[n * R], end = rp[n * R + R];
  int RD128 = R * 128;
  float2 s0 = {0.f, 0.f}, s1 = {0.f, 0.f};
  int i = beg;
  for (; i + 1 < end; i += 2){
    int v0 = pack[i], v1 = pack[i + 1];
    float al0 = alp[i], al1 = alp[i + 1];
    const unsigned short* p0 = xw + (size_t)(v0 & 0x7ffffff) * RD128 + (v0 >> 27) * 128 + 2 * ln;
    const unsigned short* p1 = xw + (size_t)(v1 & 0x7ffffff) * RD128 + (v1 >> 27) * 128 + 2 * ln;
    unsigned u0 = *(const unsigned*)p0;
    unsigned u1 = *(const unsigned*)p1;
    s0.x += al0 * __uint_as_float(u0 << 16);
    s0.y += al0 * __uint_as_float(u0 & 0xffff0000u);
    s1.x += al1 * __uint_as_float(u1 << 16);
    s1.y += al1 * __uint_as_float(u1 & 0xffff0000u);
  }
  if (i < end){
    int v0 = pack[i];
    float al0 = alp[i];
    const unsigned short* p0 = xw + (size_t)(v0 & 0x7ffffff) * RD128 + (v0 >> 27) * 128 + 2 * ln;
    unsigned u0 = *(const unsigned*)p0;
    s0.x += al0 * __uint_as_float(u0 << 16);
    s0.y += al0 * __uint_as_float(u0 & 0xffff0000u);
  }
  float2 o;
  o.x = fmaxf(s0.x + s1.x + bias[2 * ln], 0.f);
  o.y = fmaxf(s0.y + s1.y + bias[2 * ln + 1], 0.f);
  ((float2*)(xo + (size_t)n * D))[ln] = o;
}

// ---- fallback: fused aggregate (S-tile in LDS) + MFMA GEMM + bias + relu ----
__global__ __launch_bounds__(256) void k_agg(const float* __restrict__ x_in,
    const unsigned short* __restrict__ wbf, const float* __restrict__ bias,
    const int* __restrict__ rp, const int* __restrict__ pack,
    const float* __restrict__ alp, float* __restrict__ x_out, int N, int R){
  __shared__ float st[64][132];
  __shared__ unsigned short wt[128][136];
  int wv = threadIdx.x >> 6, ln = threadIdx.x & 63;
  int g = ln >> 4, m16 = ln & 15;
  int n0 = blockIdx.x * 64;
  f32x4 acc[8];
#pragma unroll
  for (int i = 0; i < 8; ++i) acc[i] = (f32x4){0.f, 0.f, 0.f, 0.f};

  for (int r = 0; r < R; ++r){
    __syncthreads();
    {
      const uint4* src = (const uint4*)(wbf + (size_t)r * 16384);
      for (int i = threadIdx.x; i < 2048; i += 256){
        int h = i >> 4, dblk = i & 15;
        *(uint4*)&wt[h][dblk * 8] = src[i];
      }
    }
    for (int j = 0; j < 16; ++j){
      int n = n0 + wv * 16 + j;
      float2 s2 = {0.f, 0.f};
      if (n < N){
        int beg = rp[n * R + r], end = rp[n * R + r + 1];
        for (int i = beg; i < end; ++i){
          int s = pack[i] & 0x7ffffff;
          float al = alp[i];
          float2 xv = ((const float2*)(x_in + (size_t)s * D))[ln];
          s2.x += al * xv.x; s2.y += al * xv.y;
        }
      }
      *(float2*)&st[wv * 16 + j][2 * ln] = s2;
    }
    __syncthreads();
#pragma unroll
    for (int kc = 0; kc < 4; ++kc){
      const float* ap = &st[wv * 16 + m16][kc * 32 + g * 8];
      float4 a0 = *(const float4*)ap;
      float4 a1 = *(const float4*)(ap + 4);
      bf16x8 af;
      af[0] = (short)f2bf(a0.x); af[1] = (short)f2bf(a0.y);
      af[2] = (short)f2bf(a0.z); af[3] = (short)f2bf(a0.w);
      af[4] = (short)f2bf(a1.x); af[5] = (short)f2bf(a1.y);
      af[6] = (short)f2bf(a1.z); af[7] = (short)f2bf(a1.w);
#pragma unroll
      for (int hf = 0; hf < 8; ++hf){
        bf16x8 bfr = *(const bf16x8*)&wt[hf * 16 + m16][kc * 32 + g * 8];
        acc[hf] = __builtin_amdgcn_mfma_f32_16x16x32_bf16(af, bfr, acc[hf], 0, 0, 0);
      }
    }
  }
#pragma unroll
  for (int hf = 0; hf < 8; ++hf){
    int h = hf * 16 + m16;
    float bv = bias[h];
#pragma unroll
    for (int jj = 0; jj < 4; ++jj){
      int n = n0 + wv * 16 + g * 4 + jj;
      if (n < N){
        float v = acc[hf][jj] + bv;
        x_out[(size_t)n * D + h] = fmaxf(v, 0.f);
      }
    }
  }
}

// ---- final linear + per-graph segment sum (atomic) ----
__global__ __launch_bounds__(256) void k_final(const float* __restrict__ x,
    const unsigned short* __restrict__ lwbf, const float* __restrict__ lb,
    const int* __restrict__ batch, float* __restrict__ out, int N){
  __shared__ unsigned short wt[128][136];
  {
    const uint4* src = (const uint4*)lwbf;
    for (int i = threadIdx.x; i < 2048; i += 256){
      int h = i >> 4, kblk = i & 15;
      *(uint4*)&wt[h][kblk * 8] = src[i];
    }
  }
  __syncthreads();
  int wv = threadIdx.x >> 6, ln = threadIdx.x & 63;
  int g = ln >> 4, m16 = ln & 15;
  int n0 = blockIdx.x * 64;
  f32x4 acc[8];
#pragma unroll
  for (int i = 0; i < 8; ++i) acc[i] = (f32x4){0.f, 0.f, 0.f, 0.f};
#pragma unroll
  for (int kc = 0; kc < 4; ++kc){
    int nA = n0 + wv * 16 + m16;
    float4 a0 = {0.f,0.f,0.f,0.f}, a1 = {0.f,0.f,0.f,0.f};
    if (nA < N){
      const float* ap = x + (size_t)nA * D + kc * 32 + g * 8;
      a0 = *(const float4*)ap; a1 = *(const float4*)(ap + 4);
    }
    bf16x8 af;
    af[0] = (short)f2bf(a0.x); af[1] = (short)f2bf(a0.y);
    af[2] = (short)f2bf(a0.z); af[3] = (short)f2bf(a0.w);
    af[4] = (short)f2bf(a1.x); af[5] = (short)f2bf(a1.y);
    af[6] = (short)f2bf(a1.z); af[7] = (short)f2bf(a1.w);
#pragma unroll
    for (int hf = 0; hf < 8; ++hf){
      bf16x8 bfr = *(const bf16x8*)&wt[hf * 16 + m16][kc * 32 + g * 8];
      acc[hf] = __builtin_amdgcn_mfma_f32_16x16x32_bf16(af, bfr, acc[hf], 0, 0, 0);
    }
  }
#pragma unroll
  for (int hf = 0; hf < 8; ++hf){
    int h = hf * 16 + m16;
    float bv = lb[h];
#pragma unroll
    for (int jj = 0; jj < 4; ++jj){
      int n = n0 + wv * 16 + g * 4 + jj;
      if (n < N){
        int bg = batch[n];
        atomicAdd(&out[(size_t)bg * D + h], acc[hf][jj] + bv);
      }
    }
  }
}

extern "C" void kernel_launch(void* const* d_in, const int* in_sizes, int n_in,
                              void* d_out, int out_size, void* d_ws, size_t ws_size,
                              hipStream_t stream){
  const int*   xpad  = (const int*)d_in[0];
  const int*   eidx  = (const int*)d_in[1];
  const int*   etyp  = (const int*)d_in[2];
  const int*   batch = (const int*)d_in[3];
  const float* emb   = (const float*)d_in[4];
  const float* w1    = (const float*)d_in[5];
  const float* q1    = (const float*)d_in[6];
  const float* k1    = (const float*)d_in[7];
  const float* b1    = (const float*)d_in[8];
  const float* w2    = (const float*)d_in[9];
  const float* q2    = (const float*)d_in[10];
  const float* k2    = (const float*)d_in[11];
  const float* b2    = (const float*)d_in[12];
  const float* lw    = (const float*)d_in[13];
  const float* lb    = (const float*)d_in[14];

  int N = in_sizes[3];
  int M = in_sizes[0] / N;
  int E = in_sizes[2];
  int R = in_sizes[5] / (128 * 128);
  int NB = N * R;
  const int* esrc = eidx;
  const int* edst = eidx + E;

  char* p = (char*)d_ws;
  auto carve = [&](size_t b) -> void* {
    void* q = (void*)p; p += (b + 255) & ~(size_t)255; return q;
  };
  float* x_a  = (float*)carve((size_t)N * D * 4);
  float* x_b  = (float*)carve((size_t)N * D * 4);
  float* wq1  = (float*)carve((size_t)R * D * 4);
  float* wk1  = (float*)carve((size_t)R * D * 4);
  float* wq2  = (float*)carve((size_t)R * D * 4);
  float* wk2  = (float*)carve((size_t)R * D * 4);
  float* aT   = (float*)carve((size_t)N * R * 4);
  float* bT   = (float*)carve((size_t)N * R * 4);
  int*   rp   = (int*)carve((size_t)(NB + 1) * 4);
  int*   cur  = (int*)carve((size_t)NB * 4);
  int*   pack = (int*)carve((size_t)E * 4);
  float* alp  = (float*)carve((size_t)E * 4);
  unsigned short* wbf1 = (unsigned short*)carve((size_t)R * 128 * 128 * 2);
  unsigned short* wbf2 = (unsigned short*)carve((size_t)R * 128 * 128 * 2);
  unsigned short* lwbf = (unsigned short*)carve((size_t)128 * 128 * 2);
  int* bsum = (int*)carve((size_t)4096 * 4);
  int* boff = (int*)carve((size_t)4096 * 4);
  if ((size_t)(p - (char*)d_ws) > ws_size) return;  // base ws too small: fail visibly
  unsigned short* xw = (unsigned short*)carve((size_t)N * R * 128 * 2);
  bool use_xw = ((size_t)(p - (char*)d_ws) <= ws_size);

  hipMemsetAsync(cur, 0, (size_t)NB * 4, stream);
  hipMemsetAsync(d_out, 0, (size_t)out_size * 4, stream);

  int eg = (E + 255) / 256;
  int nblk = (NB + 1023) / 1024;
  k_count   <<<eg, 256, 0, stream>>>(edst, etyp, cur, E, R);
  k_scan_blk<<<nblk, 256, 0, stream>>>(cur, bsum, NB);
  k_scan_top<<<1, 1024, 0, stream>>>(bsum, boff, rp, nblk, NB);
  k_scan_fin<<<nblk, 256, 0, stream>>>(cur, boff, rp, NB);
  k_scatter <<<eg, 256, 0, stream>>>(esrc, edst, etyp, cur, pack, E, R);

  k_wqk<<<(R * D + 255) / 256, 256, 0, stream>>>(w1, q1, k1, wq1, wk1, R * D);
  k_wqk<<<(R * D + 255) / 256, 256, 0, stream>>>(w2, q2, k2, wq2, wk2, R * D);
  int wtot = R * 128 * 128;
  k_wtr<<<(wtot + 255) / 256, 256, 0, stream>>>(w1, wbf1, wtot);
  k_wtr<<<(wtot + 255) / 256, 256, 0, stream>>>(w2, wbf2, wtot);
  k_cvt<<<(128 * 128 + 255) / 256, 256, 0, stream>>>(lw, lwbf, 128 * 128);

  int ng4 = (N + 3) / 4;
  int ntile = (N + 63) / 64;
  k_pool<<<ng4, 256, 0, stream>>>(xpad, emb, x_a, N, M);

  // layer 1
  k_ab   <<<ng4, 256, 0, stream>>>(x_a, wq1, wk1, aT, bT, N, R);
  k_alpha<<<ng4, 256, 0, stream>>>(rp, pack, aT, bT, alp, N, R);
  if (use_xw){
    k_xw  <<<ntile, 256, 0, stream>>>(x_a, wbf1, xw, N, R);
    k_aggX<<<ng4, 256, 0, stream>>>(xw, rp, pack, alp, b1, x_b, N, R);
  } else {
    k_agg <<<ntile, 256, 0, stream>>>(x_a, wbf1, b1, rp, pack, alp, x_b, N, R);
  }

  // layer 2
  k_ab   <<<ng4, 256, 0, stream>>>(x_b, wq2, wk2, aT, bT, N, R);
  k_alpha<<<ng4, 256, 0, stream>>>(rp, pack, aT, bT, alp, N, R);
  if (use_xw){
    k_xw  <<<ntile, 256, 0, stream>>>(x_b, wbf2, xw, N, R);
    k_aggX<<<ng4, 256, 0, stream>>>(xw, rp, pack, alp, b2, x_a, N, R);
  } else {
    k_agg <<<ntile, 256, 0, stream>>>(x_b, wbf2, b2, rp, pack, alp, x_a, N, R);
  }

  // final linear + graph segment-sum
  k_final<<<ntile, 256, 0, stream>>>(x_a, lwbf, lb, batch, (float*)d_out, N);
}

// Round 4
// 686.673 us; speedup vs baseline: 3.2569x; 1.2462x over previous
//
#include <hip/hip_runtime.h>
#include <hip/hip_bf16.h>
#include <math.h>

#define D 128

typedef __attribute__((ext_vector_type(4))) float f32x4;
typedef __attribute__((ext_vector_type(8))) short bf16x8;

__device__ inline unsigned short f2bf(float f){
  unsigned u = __float_as_uint(f);
  u += 0x7fffu + ((u >> 16) & 1u);
  return (unsigned short)(u >> 16);
}
__device__ inline float wred_sum(float v){
#pragma unroll
  for (int m = 1; m < 64; m <<= 1) v += __shfl_xor(v, m, 64);
  return v;
}
__device__ inline float wred_max(float v){
#pragma unroll
  for (int m = 1; m < 64; m <<= 1) v = fmaxf(v, __shfl_xor(v, m, 64));
  return v;
}

// ---- embedding mean-pool: wave per node ----
__global__ __launch_bounds__(256) void k_pool(const int* __restrict__ xpad,
    const float* __restrict__ emb, float* __restrict__ xo, int N, int M){
  int wv = threadIdx.x >> 6, ln = threadIdx.x & 63;
  int n = blockIdx.x * 4 + wv;
  if (n >= N) return;
  float2 acc = {0.f, 0.f}; int cnt = 0;
  for (int m = 0; m < M; ++m){
    int idx = xpad[n * M + m];
    if (idx >= 0){
      const float2* er = (const float2*)(emb + (size_t)idx * D);
      float2 v = er[ln];
      acc.x += v.x; acc.y += v.y; ++cnt;
    }
  }
  float inv = 1.f / (float)cnt;
  float2 o; o.x = acc.x * inv; o.y = acc.y * inv;
  ((float2*)(xo + (size_t)n * D))[ln] = o;
}

// ---- CSR build over buckets (dst*R + et) ----
__global__ void k_count(const int* __restrict__ dst, const int* __restrict__ et,
                        int* __restrict__ cnt, int E, int R){
  int e = blockIdx.x * 256 + threadIdx.x;
  if (e < E) atomicAdd(&cnt[dst[e] * R + et[e]], 1);
}

// ---- hierarchical exclusive scan over nb buckets (1024 elems / block) ----
__global__ __launch_bounds__(256) void k_scan_blk(const int* __restrict__ cc,
    int* __restrict__ bsum, int nb){
  __shared__ int sh[256];
  int base = blockIdx.x * 1024 + threadIdx.x * 4;
  int s = 0;
#pragma unroll
  for (int j = 0; j < 4; ++j){
    int i = base + j;
    if (i < nb) s += cc[i];
  }
  sh[threadIdx.x] = s; __syncthreads();
  for (int off = 128; off > 0; off >>= 1){
    if (threadIdx.x < off) sh[threadIdx.x] += sh[threadIdx.x + off];
    __syncthreads();
  }
  if (threadIdx.x == 0) bsum[blockIdx.x] = sh[0];
}

__global__ __launch_bounds__(1024) void k_scan_top(const int* __restrict__ bsum,
    int* __restrict__ boff, int* __restrict__ rp, int nblk, int nb){
  __shared__ int sh[1024];
  int t = threadIdx.x;
  int v = (t < nblk) ? bsum[t] : 0;
  sh[t] = v; __syncthreads();
  for (int off = 1; off < 1024; off <<= 1){
    int a = sh[t];
    int b = (t >= off) ? sh[t - off] : 0;
    __syncthreads();
    sh[t] = a + b;
    __syncthreads();
  }
  if (t < nblk) boff[t] = sh[t] - v;       // exclusive
  if (t == 1023) rp[nb] = sh[1023];        // total
}

__global__ __launch_bounds__(256) void k_scan_fin(int* __restrict__ cc,
    const int* __restrict__ boff, int* __restrict__ rp, int nb){
  __shared__ int sh[256];
  int t = threadIdx.x;
  int base = blockIdx.x * 1024 + t * 4;
  int c[4]; int local = 0;
#pragma unroll
  for (int j = 0; j < 4; ++j){
    int i = base + j;
    c[j] = (i < nb) ? cc[i] : 0;
    local += c[j];
  }
  sh[t] = local; __syncthreads();
  for (int off = 1; off < 256; off <<= 1){
    int a = sh[t];
    int b = (t >= off) ? sh[t - off] : 0;
    __syncthreads();
    sh[t] = a + b;
    __syncthreads();
  }
  int run = sh[t] - local + boff[blockIdx.x];
#pragma unroll
  for (int j = 0; j < 4; ++j){
    int i = base + j;
    if (i < nb){ rp[i] = run; cc[i] = run; run += c[j]; }
  }
}

__global__ void k_scatter(const int* __restrict__ src, const int* __restrict__ dst,
    const int* __restrict__ et, int* __restrict__ cur, int* __restrict__ pack, int E, int R){
  int e = blockIdx.x * 256 + threadIdx.x;
  if (e < E){
    int t = et[e];
    int p = atomicAdd(&cur[dst[e] * R + t], 1);
    pack[p] = (t << 27) | src[e];
  }
}

// ---- wq[r][d] = sum_h w[r][d][h]*q[h]; wk likewise ----
__global__ void k_wqk(const float* __restrict__ w, const float* __restrict__ q,
    const float* __restrict__ kk, float* __restrict__ wq, float* __restrict__ wk, int RD){
  int id = blockIdx.x * 256 + threadIdx.x;
  if (id >= RD) return;
  const float* wr = w + (size_t)id * D;
  float sq = 0.f, sk = 0.f;
  for (int h = 0; h < D; ++h){ float v = wr[h]; sq += v * q[h]; sk += v * kk[h]; }
  wq[id] = sq; wk[id] = sk;
}

// ---- w[r][d][h] fp32 -> wbf[r][h][d] bf16 (transposed) ----
__global__ void k_wtr(const float* __restrict__ w, unsigned short* __restrict__ wbf, int total){
  int id = blockIdx.x * 256 + threadIdx.x;
  if (id >= total) return;
  int d = id & 127, h = (id >> 7) & 127, r = id >> 14;
  wbf[id] = f2bf(w[(size_t)r * 16384 + d * 128 + h]);
}

// ---- plain fp32 -> bf16 convert (no transpose) ----
__global__ void k_cvt(const float* __restrict__ s, unsigned short* __restrict__ dd, int total){
  int id = blockIdx.x * 256 + threadIdx.x;
  if (id < total) dd[id] = f2bf(s[id]);
}

// ---- a[n,r]=x[n].wq[r], b[n,r]=x[n].wk[r]: wave per node ----
__global__ __launch_bounds__(256) void k_ab(const float* __restrict__ x,
    const float* __restrict__ wq, const float* __restrict__ wk,
    float* __restrict__ aT, float* __restrict__ bT, int N, int R){
  __shared__ float lq[8 * D], lk[8 * D];
  for (int i = threadIdx.x; i < R * D; i += 256){ lq[i] = wq[i]; lk[i] = wk[i]; }
  __syncthreads();
  int wv = threadIdx.x >> 6, ln = threadIdx.x & 63;
  int n = blockIdx.x * 4 + wv;
  if (n >= N) return;
  float2 xv = ((const float2*)(x + (size_t)n * D))[ln];
  for (int r = 0; r < R; ++r){
    float pa = xv.x * lq[r * D + 2 * ln] + xv.y * lq[r * D + 2 * ln + 1];
    float pb = xv.x * lk[r * D + 2 * ln] + xv.y * lk[r * D + 2 * ln + 1];
    pa = wred_sum(pa); pb = wred_sum(pb);
    if (ln == 0){ aT[n * R + r] = pa; bT[n * R + r] = pb; }
  }
}

// ---- segment softmax over dst: wave per node ----
__global__ __launch_bounds__(256) void k_alpha(const int* __restrict__ rp,
    const int* __restrict__ pack, const float* __restrict__ aT, const float* __restrict__ bT,
    float* __restrict__ alp, int N, int R){
  int wv = threadIdx.x >> 6, ln = threadIdx.x & 63;
  int n = blockIdx.x * 4 + wv;
  if (n >= N) return;
  int beg = rp[n * R], end = rp[n * R + R];
  if (end <= beg) return;
  float mx = -3.4e38f;
  for (int i = beg + ln; i < end; i += 64){
    int v = pack[i]; int t = v >> 27; int s = v & 0x7ffffff;
    float l = aT[n * R + t] + bT[s * R + t];
    l = l > 0.f ? l : 0.2f * l;
    mx = fmaxf(mx, l);
  }
  mx = wred_max(mx);
  float sm = 0.f;
  for (int i = beg + ln; i < end; i += 64){
    int v = pack[i]; int t = v >> 27; int s = v & 0x7ffffff;
    float l = aT[n * R + t] + bT[s * R + t];
    l = l > 0.f ? l : 0.2f * l;
    float ev = __expf(l - mx);
    alp[i] = ev; sm += ev;
  }
  sm = wred_sum(sm);
  float inv = 1.f / sm;
  for (int i = beg + ln; i < end; i += 64) alp[i] *= inv;
}

// ---- xw[n][r*128+h] = (x[n] @ w[r])[h], bf16, via MFMA; B read from L1/L2 ----
__global__ __launch_bounds__(256) void k_xw(const float* __restrict__ x,
    const unsigned short* __restrict__ wbf,  // [R][h][k] bf16
    unsigned short* __restrict__ xw,         // [N][R*128] bf16
    int N, int R){
  int wv = threadIdx.x >> 6, ln = threadIdx.x & 63;
  int g = ln >> 4, m16 = ln & 15;
  int n0 = blockIdx.x * 64;
  int nA = n0 + wv * 16 + m16;
  bf16x8 af[4];
#pragma unroll
  for (int kc = 0; kc < 4; ++kc){
    float4 a0 = {0.f,0.f,0.f,0.f}, a1 = {0.f,0.f,0.f,0.f};
    if (nA < N){
      const float* ap = x + (size_t)nA * D + kc * 32 + g * 8;
      a0 = *(const float4*)ap; a1 = *(const float4*)(ap + 4);
    }
    af[kc][0] = (short)f2bf(a0.x); af[kc][1] = (short)f2bf(a0.y);
    af[kc][2] = (short)f2bf(a0.z); af[kc][3] = (short)f2bf(a0.w);
    af[kc][4] = (short)f2bf(a1.x); af[kc][5] = (short)f2bf(a1.y);
    af[kc][6] = (short)f2bf(a1.z); af[kc][7] = (short)f2bf(a1.w);
  }
  int RD128 = R * 128;
  for (int r = 0; r < R; ++r){
    f32x4 acc[8];
#pragma unroll
    for (int i = 0; i < 8; ++i) acc[i] = (f32x4){0.f, 0.f, 0.f, 0.f};
    const unsigned short* wr = wbf + (size_t)r * 16384;
#pragma unroll
    for (int kc = 0; kc < 4; ++kc){
#pragma unroll
      for (int hf = 0; hf < 8; ++hf){
        bf16x8 bfr = *(const bf16x8*)(wr + (hf * 16 + m16) * 128 + kc * 32 + g * 8);
        acc[hf] = __builtin_amdgcn_mfma_f32_16x16x32_bf16(af[kc], bfr, acc[hf], 0, 0, 0);
      }
    }
#pragma unroll
    for (int hf = 0; hf < 8; ++hf){
#pragma unroll
      for (int jj = 0; jj < 4; ++jj){
        int n = n0 + wv * 16 + g * 4 + jj;
        if (n < N) xw[(size_t)n * RD128 + r * 128 + hf * 16 + m16] = f2bf(acc[hf][jj]);
      }
    }
  }
}

// ---- aggregation: one wave per node, flat edge range, gather xw rows ----
__global__ __launch_bounds__(256) void k_aggX(const unsigned short* __restrict__ xw,
    const int* __restrict__ rp, const int* __restrict__ pack, const float* __restrict__ alp,
    const float* __restrict__ bias, float* __restrict__ xo, int N, int R){
  int wv = threadIdx.x >> 6, ln = threadIdx.x & 63;
  int n = blockIdx.x * 4 + wv;
  if (n >= N) return;
  int beg = rp[n * R], end = rp[n * R + R];
  int RD128 = R * 128;
  float2 s0 = {0.f, 0.f}, s1 = {0.f, 0.f};
  int i = beg;
  for (; i + 1 < end; i += 2){
    int v0 = pack[i], v1 = pack[i + 1];
    float al0 = alp[i], al1 = alp[i + 1];
    const unsigned short* p0 = xw + (size_t)(v0 & 0x7ffffff) * RD128 + (v0 >> 27) * 128 + 2 * ln;
    const unsigned short* p1 = xw + (size_t)(v1 & 0x7ffffff) * RD128 + (v1 >> 27) * 128 + 2 * ln;
    unsigned u0 = *(const unsigned*)p0;
    unsigned u1 = *(const unsigned*)p1;
    s0.x += al0 * __uint_as_float(u0 << 16);
    s0.y += al0 * __uint_as_float(u0 & 0xffff0000u);
    s1.x += al1 * __uint_as_float(u1 << 16);
    s1.y += al1 * __uint_as_float(u1 & 0xffff0000u);
  }
  if (i < end){
    int v0 = pack[i];
    float al0 = alp[i];
    const unsigned short* p0 = xw + (size_t)(v0 & 0x7ffffff) * RD128 + (v0 >> 27) * 128 + 2 * ln;
    unsigned u0 = *(const unsigned*)p0;
    s0.x += al0 * __uint_as_float(u0 << 16);
    s0.y += al0 * __uint_as_float(u0 & 0xffff0000u);
  }
  float2 o;
  o.x = fmaxf(s0.x + s1.x + bias[2 * ln], 0.f);
  o.y = fmaxf(s0.y + s1.y + bias[2 * ln + 1], 0.f);
  ((float2*)(xo + (size_t)n * D))[ln] = o;
}

// ---- fallback: fused aggregate (S-tile in LDS) + MFMA GEMM + bias + relu ----
__global__ __launch_bounds__(256) void k_agg(const float* __restrict__ x_in,
    const unsigned short* __restrict__ wbf, const float* __restrict__ bias,
    const int* __restrict__ rp, const int* __restrict__ pack,
    const float* __restrict__ alp, float* __restrict__ x_out, int N, int R){
  __shared__ float st[64][132];
  __shared__ unsigned short wt[128][136];
  int wv = threadIdx.x >> 6, ln = threadIdx.x & 63;
  int g = ln >> 4, m16 = ln & 15;
  int n0 = blockIdx.x * 64;
  f32x4 acc[8];
#pragma unroll
  for (int i = 0; i < 8; ++i) acc[i] = (f32x4){0.f, 0.f, 0.f, 0.f};

  for (int r = 0; r < R; ++r){
    __syncthreads();
    {
      const uint4* src = (const uint4*)(wbf + (size_t)r * 16384);
      for (int i = threadIdx.x; i < 2048; i += 256){
        int h = i >> 4, dblk = i & 15;
        *(uint4*)&wt[h][dblk * 8] = src[i];
      }
    }
    for (int j = 0; j < 16; ++j){
      int n = n0 + wv * 16 + j;
      float2 s2 = {0.f, 0.f};
      if (n < N){
        int beg = rp[n * R + r], end = rp[n * R + r + 1];
        for (int i = beg; i < end; ++i){
          int s = pack[i] & 0x7ffffff;
          float al = alp[i];
          float2 xv = ((const float2*)(x_in + (size_t)s * D))[ln];
          s2.x += al * xv.x; s2.y += al * xv.y;
        }
      }
      *(float2*)&st[wv * 16 + j][2 * ln] = s2;
    }
    __syncthreads();
#pragma unroll
    for (int kc = 0; kc < 4; ++kc){
      const float* ap = &st[wv * 16 + m16][kc * 32 + g * 8];
      float4 a0 = *(const float4*)ap;
      float4 a1 = *(const float4*)(ap + 4);
      bf16x8 af;
      af[0] = (short)f2bf(a0.x); af[1] = (short)f2bf(a0.y);
      af[2] = (short)f2bf(a0.z); af[3] = (short)f2bf(a0.w);
      af[4] = (short)f2bf(a1.x); af[5] = (short)f2bf(a1.y);
      af[6] = (short)f2bf(a1.z); af[7] = (short)f2bf(a1.w);
#pragma unroll
      for (int hf = 0; hf < 8; ++hf){
        bf16x8 bfr = *(const bf16x8*)&wt[hf * 16 + m16][kc * 32 + g * 8];
        acc[hf] = __builtin_amdgcn_mfma_f32_16x16x32_bf16(af, bfr, acc[hf], 0, 0, 0);
      }
    }
  }
#pragma unroll
  for (int hf = 0; hf < 8; ++hf){
    int h = hf * 16 + m16;
    float bv = bias[h];
#pragma unroll
    for (int jj = 0; jj < 4; ++jj){
      int n = n0 + wv * 16 + g * 4 + jj;
      if (n < N){
        float v = acc[hf][jj] + bv;
        x_out[(size_t)n * D + h] = fmaxf(v, 0.f);
      }
    }
  }
}

// ---- final linear + per-graph segment sum: LDS per-block reduce over sorted
// batch runs, then ONE atomicAdd per (graph,h) run present in the tile ----
__global__ __launch_bounds__(256) void k_final(const float* __restrict__ x,
    const unsigned short* __restrict__ lwbf, const float* __restrict__ lb,
    const int* __restrict__ batch, float* __restrict__ out, int N){
  __shared__ unsigned short wt[128][136]; // lin_w [h][k] bf16
  __shared__ float st[64][129];           // per-node output rows
  __shared__ int bsh[64];
  {
    const uint4* src = (const uint4*)lwbf;
    for (int i = threadIdx.x; i < 2048; i += 256){
      int h = i >> 4, kblk = i & 15;
      *(uint4*)&wt[h][kblk * 8] = src[i];
    }
  }
  __syncthreads();
  int wv = threadIdx.x >> 6, ln = threadIdx.x & 63;
  int g = ln >> 4, m16 = ln & 15;
  int n0 = blockIdx.x * 64;
  f32x4 acc[8];
#pragma unroll
  for (int i = 0; i < 8; ++i) acc[i] = (f32x4){0.f, 0.f, 0.f, 0.f};
#pragma unroll
  for (int kc = 0; kc < 4; ++kc){
    int nA = n0 + wv * 16 + m16;
    float4 a0 = {0.f,0.f,0.f,0.f}, a1 = {0.f,0.f,0.f,0.f};
    if (nA < N){
      const float* ap = x + (size_t)nA * D + kc * 32 + g * 8;
      a0 = *(const float4*)ap; a1 = *(const float4*)(ap + 4);
    }
    bf16x8 af;
    af[0] = (short)f2bf(a0.x); af[1] = (short)f2bf(a0.y);
    af[2] = (short)f2bf(a0.z); af[3] = (short)f2bf(a0.w);
    af[4] = (short)f2bf(a1.x); af[5] = (short)f2bf(a1.y);
    af[6] = (short)f2bf(a1.z); af[7] = (short)f2bf(a1.w);
#pragma unroll
    for (int hf = 0; hf < 8; ++hf){
      bf16x8 bfr = *(const bf16x8*)&wt[hf * 16 + m16][kc * 32 + g * 8];
      acc[hf] = __builtin_amdgcn_mfma_f32_16x16x32_bf16(af, bfr, acc[hf], 0, 0, 0);
    }
  }
  // rows -> LDS (per-node bias added here; invalid rows zeroed)
#pragma unroll
  for (int hf = 0; hf < 8; ++hf){
    int h = hf * 16 + m16;
    float bv = lb[h];
#pragma unroll
    for (int jj = 0; jj < 4; ++jj){
      int row = wv * 16 + g * 4 + jj;
      int n = n0 + row;
      st[row][h] = (n < N) ? (acc[hf][jj] + bv) : 0.f;
    }
  }
  if (threadIdx.x < 64){
    int n = n0 + threadIdx.x;
    bsh[threadIdx.x] = (n < N) ? batch[n] : -1;
  }
  __syncthreads();
  // scan sorted rows, one atomic per (graph,h) run
  if (threadIdx.x < 128){
    int h = threadIdx.x;
    int lastValid = (N - n0 < 64) ? (N - n0 - 1) : 63;
    int cg = bsh[0];
    float sum = 0.f;
    for (int row = 0; row <= lastValid; ++row){
      int bg = bsh[row];
      if (bg != cg){
        atomicAdd(&out[(size_t)cg * D + h], sum);
        sum = 0.f; cg = bg;
      }
      sum += st[row][h];
    }
    atomicAdd(&out[(size_t)cg * D + h], sum);
  }
}

extern "C" void kernel_launch(void* const* d_in, const int* in_sizes, int n_in,
                              void* d_out, int out_size, void* d_ws, size_t ws_size,
                              hipStream_t stream){
  const int*   xpad  = (const int*)d_in[0];
  const int*   eidx  = (const int*)d_in[1];
  const int*   etyp  = (const int*)d_in[2];
  const int*   batch = (const int*)d_in[3];
  const float* emb   = (const float*)d_in[4];
  const float* w1    = (const float*)d_in[5];
  const float* q1    = (const float*)d_in[6];
  const float* k1    = (const float*)d_in[7];
  const float* b1    = (const float*)d_in[8];
  const float* w2    = (const float*)d_in[9];
  const float* q2    = (const float*)d_in[10];
  const float* k2    = (const float*)d_in[11];
  const float* b2    = (const float*)d_in[12];
  const float* lw    = (const float*)d_in[13];
  const float* lb    = (const float*)d_in[14];

  int N = in_sizes[3];
  int M = in_sizes[0] / N;
  int E = in_sizes[2];
  int R = in_sizes[5] / (128 * 128);
  int NB = N * R;
  const int* esrc = eidx;
  const int* edst = eidx + E;

  char* p = (char*)d_ws;
  auto carve = [&](size_t b) -> void* {
    void* q = (void*)p; p += (b + 255) & ~(size_t)255; return q;
  };
  float* x_a  = (float*)carve((size_t)N * D * 4);
  float* x_b  = (float*)carve((size_t)N * D * 4);
  float* wq1  = (float*)carve((size_t)R * D * 4);
  float* wk1  = (float*)carve((size_t)R * D * 4);
  float* wq2  = (float*)carve((size_t)R * D * 4);
  float* wk2  = (float*)carve((size_t)R * D * 4);
  float* aT   = (float*)carve((size_t)N * R * 4);
  float* bT   = (float*)carve((size_t)N * R * 4);
  int*   rp   = (int*)carve((size_t)(NB + 1) * 4);
  int*   cur  = (int*)carve((size_t)NB * 4);
  int*   pack = (int*)carve((size_t)E * 4);
  float* alp  = (float*)carve((size_t)E * 4);
  unsigned short* wbf1 = (unsigned short*)carve((size_t)R * 128 * 128 * 2);
  unsigned short* wbf2 = (unsigned short*)carve((size_t)R * 128 * 128 * 2);
  unsigned short* lwbf = (unsigned short*)carve((size_t)128 * 128 * 2);
  int* bsum = (int*)carve((size_t)4096 * 4);
  int* boff = (int*)carve((size_t)4096 * 4);
  if ((size_t)(p - (char*)d_ws) > ws_size) return;  // base ws too small: fail visibly
  unsigned short* xw = (unsigned short*)carve((size_t)N * R * 128 * 2);
  bool use_xw = ((size_t)(p - (char*)d_ws) <= ws_size);

  hipMemsetAsync(cur, 0, (size_t)NB * 4, stream);
  hipMemsetAsync(d_out, 0, (size_t)out_size * 4, stream);

  int eg = (E + 255) / 256;
  int nblk = (NB + 1023) / 1024;
  k_count   <<<eg, 256, 0, stream>>>(edst, etyp, cur, E, R);
  k_scan_blk<<<nblk, 256, 0, stream>>>(cur, bsum, NB);
  k_scan_top<<<1, 1024, 0, stream>>>(bsum, boff, rp, nblk, NB);
  k_scan_fin<<<nblk, 256, 0, stream>>>(cur, boff, rp, NB);
  k_scatter <<<eg, 256, 0, stream>>>(esrc, edst, etyp, cur, pack, E, R);

  k_wqk<<<(R * D + 255) / 256, 256, 0, stream>>>(w1, q1, k1, wq1, wk1, R * D);
  k_wqk<<<(R * D + 255) / 256, 256, 0, stream>>>(w2, q2, k2, wq2, wk2, R * D);
  int wtot = R * 128 * 128;
  k_wtr<<<(wtot + 255) / 256, 256, 0, stream>>>(w1, wbf1, wtot);
  k_wtr<<<(wtot + 255) / 256, 256, 0, stream>>>(w2, wbf2, wtot);
  k_cvt<<<(128 * 128 + 255) / 256, 256, 0, stream>>>(lw, lwbf, 128 * 128);

  int ng4 = (N + 3) / 4;
  int ntile = (N + 63) / 64;
  k_pool<<<ng4, 256, 0, stream>>>(xpad, emb, x_a, N, M);

  // layer 1
  k_ab   <<<ng4, 256, 0, stream>>>(x_a, wq1, wk1, aT, bT, N, R);
  k_alpha<<<ng4, 256, 0, stream>>>(rp, pack, aT, bT, alp, N, R);
  if (use_xw){
    k_xw  <<<ntile, 256, 0, stream>>>(x_a, wbf1, xw, N, R);
    k_aggX<<<ng4, 256, 0, stream>>>(xw, rp, pack, alp, b1, x_b, N, R);
  } else {
    k_agg <<<ntile, 256, 0, stream>>>(x_a, wbf1, b1, rp, pack, alp, x_b, N, R);
  }

  // layer 2
  k_ab   <<<ng4, 256, 0, stream>>>(x_b, wq2, wk2, aT, bT, N, R);
  k_alpha<<<ng4, 256, 0, stream>>>(rp, pack, aT, bT, alp, N, R);
  if (use_xw){
    k_xw  <<<ntile, 256, 0, stream>>>(x_b, wbf2, xw, N, R);
    k_aggX<<<ng4, 256, 0, stream>>>(xw, rp, pack, alp, b2, x_a, N, R);
  } else {
    k_agg <<<ntile, 256, 0, stream>>>(x_b, wbf2, b2, rp, pack, alp, x_a, N, R);
  }

  // final linear + graph segment-sum
  k_final<<<ntile, 256, 0, stream>>>(x_a, lwbf, lb, batch, (float*)d_out, N);
}

// Round 5
// 679.543 us; speedup vs baseline: 3.2911x; 1.0105x over previous
//
#include <hip/hip_runtime.h>
#include <hip/hip_bf16.h>
#include <math.h>

#define D 128

typedef __attribute__((ext_vector_type(4))) float f32x4;
typedef __attribute__((ext_vector_type(8))) short bf16x8;

__device__ inline unsigned short f2bf(float f){
  unsigned u = __float_as_uint(f);
  u += 0x7fffu + ((u >> 16) & 1u);
  return (unsigned short)(u >> 16);
}
__device__ inline float wred_sum(float v){
#pragma unroll
  for (int m = 1; m < 64; m <<= 1) v += __shfl_xor(v, m, 64);
  return v;
}
__device__ inline float wred_max(float v){
#pragma unroll
  for (int m = 1; m < 64; m <<= 1) v = fmaxf(v, __shfl_xor(v, m, 64));
  return v;
}

// ---- embedding mean-pool: wave per node ----
__global__ __launch_bounds__(256) void k_pool(const int* __restrict__ xpad,
    const float* __restrict__ emb, float* __restrict__ xo, int N, int M){
  int wv = threadIdx.x >> 6, ln = threadIdx.x & 63;
  int n = blockIdx.x * 4 + wv;
  if (n >= N) return;
  float2 acc = {0.f, 0.f}; int cnt = 0;
  for (int m = 0; m < M; ++m){
    int idx = xpad[n * M + m];
    if (idx >= 0){
      const float2* er = (const float2*)(emb + (size_t)idx * D);
      float2 v = er[ln];
      acc.x += v.x; acc.y += v.y; ++cnt;
    }
  }
  float inv = 1.f / (float)cnt;
  float2 o; o.x = acc.x * inv; o.y = acc.y * inv;
  ((float2*)(xo + (size_t)n * D))[ln] = o;
}

// ---- CSR build over buckets (dst*R + et) ----
__global__ void k_count(const int* __restrict__ dst, const int* __restrict__ et,
                        int* __restrict__ cnt, int E, int R){
  int e = blockIdx.x * 256 + threadIdx.x;
  if (e < E) atomicAdd(&cnt[dst[e] * R + et[e]], 1);
}

// ---- hierarchical exclusive scan over nb buckets (1024 elems / block) ----
__global__ __launch_bounds__(256) void k_scan_blk(const int* __restrict__ cc,
    int* __restrict__ bsum, int nb){
  __shared__ int sh[256];
  int base = blockIdx.x * 1024 + threadIdx.x * 4;
  int s = 0;
#pragma unroll
  for (int j = 0; j < 4; ++j){
    int i = base + j;
    if (i < nb) s += cc[i];
  }
  sh[threadIdx.x] = s; __syncthreads();
  for (int off = 128; off > 0; off >>= 1){
    if (threadIdx.x < off) sh[threadIdx.x] += sh[threadIdx.x + off];
    __syncthreads();
  }
  if (threadIdx.x == 0) bsum[blockIdx.x] = sh[0];
}

__global__ __launch_bounds__(1024) void k_scan_top(const int* __restrict__ bsum,
    int* __restrict__ boff, int* __restrict__ rp, int nblk, int nb){
  __shared__ int sh[1024];
  int t = threadIdx.x;
  int v = (t < nblk) ? bsum[t] : 0;
  sh[t] = v; __syncthreads();
  for (int off = 1; off < 1024; off <<= 1){
    int a = sh[t];
    int b = (t >= off) ? sh[t - off] : 0;
    __syncthreads();
    sh[t] = a + b;
    __syncthreads();
  }
  if (t < nblk) boff[t] = sh[t] - v;       // exclusive
  if (t == 1023) rp[nb] = sh[1023];        // total
}

__global__ __launch_bounds__(256) void k_scan_fin(int* __restrict__ cc,
    const int* __restrict__ boff, int* __restrict__ rp, int nb){
  __shared__ int sh[256];
  int t = threadIdx.x;
  int base = blockIdx.x * 1024 + t * 4;
  int c[4]; int local = 0;
#pragma unroll
  for (int j = 0; j < 4; ++j){
    int i = base + j;
    c[j] = (i < nb) ? cc[i] : 0;
    local += c[j];
  }
  sh[t] = local; __syncthreads();
  for (int off = 1; off < 256; off <<= 1){
    int a = sh[t];
    int b = (t >= off) ? sh[t - off] : 0;
    __syncthreads();
    sh[t] = a + b;
    __syncthreads();
  }
  int run = sh[t] - local + boff[blockIdx.x];
#pragma unroll
  for (int j = 0; j < 4; ++j){
    int i = base + j;
    if (i < nb){ rp[i] = run; cc[i] = run; run += c[j]; }
  }
}

__global__ void k_scatter(const int* __restrict__ src, const int* __restrict__ dst,
    const int* __restrict__ et, int* __restrict__ cur, int* __restrict__ pack, int E, int R){
  int e = blockIdx.x * 256 + threadIdx.x;
  if (e < E){
    int t = et[e];
    int p = atomicAdd(&cur[dst[e] * R + t], 1);
    pack[p] = (t << 27) | src[e];
  }
}

// ---- wq[r][d] = sum_h w[r][d][h]*q[h]; wk likewise ----
__global__ void k_wqk(const float* __restrict__ w, const float* __restrict__ q,
    const float* __restrict__ kk, float* __restrict__ wq, float* __restrict__ wk, int RD){
  int id = blockIdx.x * 256 + threadIdx.x;
  if (id >= RD) return;
  const float* wr = w + (size_t)id * D;
  float sq = 0.f, sk = 0.f;
  for (int h = 0; h < D; ++h){ float v = wr[h]; sq += v * q[h]; sk += v * kk[h]; }
  wq[id] = sq; wk[id] = sk;
}

// ---- w[r][d][h] fp32 -> wbf[r][h][d] bf16 (transposed) ----
__global__ void k_wtr(const float* __restrict__ w, unsigned short* __restrict__ wbf, int total){
  int id = blockIdx.x * 256 + threadIdx.x;
  if (id >= total) return;
  int d = id & 127, h = (id >> 7) & 127, r = id >> 14;
  wbf[id] = f2bf(w[(size_t)r * 16384 + d * 128 + h]);
}

// ---- plain fp32 -> bf16 convert (no transpose) ----
__global__ void k_cvt(const float* __restrict__ s, unsigned short* __restrict__ dd, int total){
  int id = blockIdx.x * 256 + threadIdx.x;
  if (id < total) dd[id] = f2bf(s[id]);
}

// ---- a[n,r]=x[n].wq[r], b[n,r]=x[n].wk[r]: wave per node ----
__global__ __launch_bounds__(256) void k_ab(const float* __restrict__ x,
    const float* __restrict__ wq, const float* __restrict__ wk,
    float* __restrict__ aT, float* __restrict__ bT, int N, int R){
  __shared__ float lq[8 * D], lk[8 * D];
  for (int i = threadIdx.x; i < R * D; i += 256){ lq[i] = wq[i]; lk[i] = wk[i]; }
  __syncthreads();
  int wv = threadIdx.x >> 6, ln = threadIdx.x & 63;
  int n = blockIdx.x * 4 + wv;
  if (n >= N) return;
  float2 xv = ((const float2*)(x + (size_t)n * D))[ln];
  for (int r = 0; r < R; ++r){
    float pa = xv.x * lq[r * D + 2 * ln] + xv.y * lq[r * D + 2 * ln + 1];
    float pb = xv.x * lk[r * D + 2 * ln] + xv.y * lk[r * D + 2 * ln + 1];
    pa = wred_sum(pa); pb = wred_sum(pb);
    if (ln == 0){ aT[n * R + r] = pa; bT[n * R + r] = pb; }
  }
}

// ---- segment softmax over dst: wave per node ----
__global__ __launch_bounds__(256) void k_alpha(const int* __restrict__ rp,
    const int* __restrict__ pack, const float* __restrict__ aT, const float* __restrict__ bT,
    float* __restrict__ alp, int N, int R){
  int wv = threadIdx.x >> 6, ln = threadIdx.x & 63;
  int n = blockIdx.x * 4 + wv;
  if (n >= N) return;
  int beg = rp[n * R], end = rp[n * R + R];
  if (end <= beg) return;
  float mx = -3.4e38f;
  for (int i = beg + ln; i < end; i += 64){
    int v = pack[i]; int t = v >> 27; int s = v & 0x7ffffff;
    float l = aT[n * R + t] + bT[s * R + t];
    l = l > 0.f ? l : 0.2f * l;
    mx = fmaxf(mx, l);
  }
  mx = wred_max(mx);
  float sm = 0.f;
  for (int i = beg + ln; i < end; i += 64){
    int v = pack[i]; int t = v >> 27; int s = v & 0x7ffffff;
    float l = aT[n * R + t] + bT[s * R + t];
    l = l > 0.f ? l : 0.2f * l;
    float ev = __expf(l - mx);
    alp[i] = ev; sm += ev;
  }
  sm = wred_sum(sm);
  float inv = 1.f / sm;
  for (int i = beg + ln; i < end; i += 64) alp[i] *= inv;
}

// ---- xw[n][r*128+h] = (x[n] @ w[r])[h], bf16, via MFMA;
//      LDS-staged epilogue -> coalesced uint4 stores ----
__global__ __launch_bounds__(256) void k_xw(const float* __restrict__ x,
    const unsigned short* __restrict__ wbf,  // [R][h][k] bf16
    unsigned short* __restrict__ xw,         // [N][R*128] bf16
    int N, int R){
  __shared__ unsigned short ot[64][136];     // 272B rows (17x16B): uint4-aligned
  int wv = threadIdx.x >> 6, ln = threadIdx.x & 63;
  int g = ln >> 4, m16 = ln & 15;
  int n0 = blockIdx.x * 64;
  int nA = n0 + wv * 16 + m16;
  bf16x8 af[4];
#pragma unroll
  for (int kc = 0; kc < 4; ++kc){
    float4 a0 = {0.f,0.f,0.f,0.f}, a1 = {0.f,0.f,0.f,0.f};
    if (nA < N){
      const float* ap = x + (size_t)nA * D + kc * 32 + g * 8;
      a0 = *(const float4*)ap; a1 = *(const float4*)(ap + 4);
    }
    af[kc][0] = (short)f2bf(a0.x); af[kc][1] = (short)f2bf(a0.y);
    af[kc][2] = (short)f2bf(a0.z); af[kc][3] = (short)f2bf(a0.w);
    af[kc][4] = (short)f2bf(a1.x); af[kc][5] = (short)f2bf(a1.y);
    af[kc][6] = (short)f2bf(a1.z); af[kc][7] = (short)f2bf(a1.w);
  }
  int RD128 = R * 128;
  for (int r = 0; r < R; ++r){
    f32x4 acc[8];
#pragma unroll
    for (int i = 0; i < 8; ++i) acc[i] = (f32x4){0.f, 0.f, 0.f, 0.f};
    const unsigned short* wr = wbf + (size_t)r * 16384;
#pragma unroll
    for (int kc = 0; kc < 4; ++kc){
#pragma unroll
      for (int hf = 0; hf < 8; ++hf){
        bf16x8 bfr = *(const bf16x8*)(wr + (hf * 16 + m16) * 128 + kc * 32 + g * 8);
        acc[hf] = __builtin_amdgcn_mfma_f32_16x16x32_bf16(af[kc], bfr, acc[hf], 0, 0, 0);
      }
    }
    __syncthreads();  // prior iteration's ot readers done
#pragma unroll
    for (int hf = 0; hf < 8; ++hf){
#pragma unroll
      for (int jj = 0; jj < 4; ++jj){
        ot[wv * 16 + g * 4 + jj][hf * 16 + m16] = f2bf(acc[hf][jj]);
      }
    }
    __syncthreads();
    // cooperative coalesced write: 1024 x uint4 (16 lanes cover 256B of a row)
    for (int i = threadIdx.x; i < 1024; i += 256){
      int row = i >> 4, c16 = i & 15;
      int n = n0 + row;
      if (n < N)
        *(uint4*)(xw + (size_t)n * RD128 + r * 128 + c16 * 8) = *(const uint4*)&ot[row][c16 * 8];
    }
  }
}

// ---- aggregation: one wave per node, flat edge range, gather xw rows ----
__global__ __launch_bounds__(256) void k_aggX(const unsigned short* __restrict__ xw,
    const int* __restrict__ rp, const int* __restrict__ pack, const float* __restrict__ alp,
    const float* __restrict__ bias, float* __restrict__ xo, int N, int R){
  int wv = threadIdx.x >> 6, ln = threadIdx.x & 63;
  int n = blockIdx.x * 4 + wv;
  if (n >= N) return;
  int beg = rp[n * R], end = rp[n * R + R];
  int RD128 = R * 128;
  float2 s0 = {0.f, 0.f}, s1 = {0.f, 0.f};
  int i = beg;
  for (; i + 1 < end; i += 2){
    int v0 = pack[i], v1 = pack[i + 1];
    float al0 = alp[i], al1 = alp[i + 1];
    const unsigned short* p0 = xw + (size_t)(v0 & 0x7ffffff) * RD128 + (v0 >> 27) * 128 + 2 * ln;
    const unsigned short* p1 = xw + (size_t)(v1 & 0x7ffffff) * RD128 + (v1 >> 27) * 128 + 2 * ln;
    unsigned u0 = *(const unsigned*)p0;
    unsigned u1 = *(const unsigned*)p1;
    s0.x += al0 * __uint_as_float(u0 << 16);
    s0.y += al0 * __uint_as_float(u0 & 0xffff0000u);
    s1.x += al1 * __uint_as_float(u1 << 16);
    s1.y += al1 * __uint_as_float(u1 & 0xffff0000u);
  }
  if (i < end){
    int v0 = pack[i];
    float al0 = alp[i];
    const unsigned short* p0 = xw + (size_t)(v0 & 0x7ffffff) * RD128 + (v0 >> 27) * 128 + 2 * ln;
    unsigned u0 = *(const unsigned*)p0;
    s0.x += al0 * __uint_as_float(u0 << 16);
    s0.y += al0 * __uint_as_float(u0 & 0xffff0000u);
  }
  float2 o;
  o.x = fmaxf(s0.x + s1.x + bias[2 * ln], 0.f);
  o.y = fmaxf(s0.y + s1.y + bias[2 * ln + 1], 0.f);
  ((float2*)(xo + (size_t)n * D))[ln] = o;
}

// ---- fallback: fused aggregate (S-tile in LDS) + MFMA GEMM + bias + relu ----
__global__ __launch_bounds__(256) void k_agg(const float* __restrict__ x_in,
    const unsigned short* __restrict__ wbf, const float* __restrict__ bias,
    const int* __restrict__ rp, const int* __restrict__ pack,
    const float* __restrict__ alp, float* __restrict__ x_out, int N, int R){
  __shared__ float st[64][132];
  __shared__ unsigned short wt[128][136];
  int wv = threadIdx.x >> 6, ln = threadIdx.x & 63;
  int g = ln >> 4, m16 = ln & 15;
  int n0 = blockIdx.x * 64;
  f32x4 acc[8];
#pragma unroll
  for (int i = 0; i < 8; ++i) acc[i] = (f32x4){0.f, 0.f, 0.f, 0.f};

  for (int r = 0; r < R; ++r){
    __syncthreads();
    {
      const uint4* src = (const uint4*)(wbf + (size_t)r * 16384);
      for (int i = threadIdx.x; i < 2048; i += 256){
        int h = i >> 4, dblk = i & 15;
        *(uint4*)&wt[h][dblk * 8] = src[i];
      }
    }
    for (int j = 0; j < 16; ++j){
      int n = n0 + wv * 16 + j;
      float2 s2 = {0.f, 0.f};
      if (n < N){
        int beg = rp[n * R + r], end = rp[n * R + r + 1];
        for (int i = beg; i < end; ++i){
          int s = pack[i] & 0x7ffffff;
          float al = alp[i];
          float2 xv = ((const float2*)(x_in + (size_t)s * D))[ln];
          s2.x += al * xv.x; s2.y += al * xv.y;
        }
      }
      *(float2*)&st[wv * 16 + j][2 * ln] = s2;
    }
    __syncthreads();
#pragma unroll
    for (int kc = 0; kc < 4; ++kc){
      const float* ap = &st[wv * 16 + m16][kc * 32 + g * 8];
      float4 a0 = *(const float4*)ap;
      float4 a1 = *(const float4*)(ap + 4);
      bf16x8 af;
      af[0] = (short)f2bf(a0.x); af[1] = (short)f2bf(a0.y);
      af[2] = (short)f2bf(a0.z); af[3] = (short)f2bf(a0.w);
      af[4] = (short)f2bf(a1.x); af[5] = (short)f2bf(a1.y);
      af[6] = (short)f2bf(a1.z); af[7] = (short)f2bf(a1.w);
#pragma unroll
      for (int hf = 0; hf < 8; ++hf){
        bf16x8 bfr = *(const bf16x8*)&wt[hf * 16 + m16][kc * 32 + g * 8];
        acc[hf] = __builtin_amdgcn_mfma_f32_16x16x32_bf16(af, bfr, acc[hf], 0, 0, 0);
      }
    }
  }
#pragma unroll
  for (int hf = 0; hf < 8; ++hf){
    int h = hf * 16 + m16;
    float bv = bias[h];
#pragma unroll
    for (int jj = 0; jj < 4; ++jj){
      int n = n0 + wv * 16 + g * 4 + jj;
      if (n < N){
        float v = acc[hf][jj] + bv;
        x_out[(size_t)n * D + h] = fmaxf(v, 0.f);
      }
    }
  }
}

// ---- final linear + per-graph segment sum: LDS per-block reduce over sorted
// batch runs, then ONE atomicAdd per (graph,h) run present in the tile ----
__global__ __launch_bounds__(256) void k_final(const float* __restrict__ x,
    const unsigned short* __restrict__ lwbf, const float* __restrict__ lb,
    const int* __restrict__ batch, float* __restrict__ out, int N){
  __shared__ unsigned short wt[128][136]; // lin_w [h][k] bf16
  __shared__ float st[64][129];           // per-node output rows
  __shared__ int bsh[64];
  {
    const uint4* src = (const uint4*)lwbf;
    for (int i = threadIdx.x; i < 2048; i += 256){
      int h = i >> 4, kblk = i & 15;
      *(uint4*)&wt[h][kblk * 8] = src[i];
    }
  }
  __syncthreads();
  int wv = threadIdx.x >> 6, ln = threadIdx.x & 63;
  int g = ln >> 4, m16 = ln & 15;
  int n0 = blockIdx.x * 64;
  f32x4 acc[8];
#pragma unroll
  for (int i = 0; i < 8; ++i) acc[i] = (f32x4){0.f, 0.f, 0.f, 0.f};
#pragma unroll
  for (int kc = 0; kc < 4; ++kc){
    int nA = n0 + wv * 16 + m16;
    float4 a0 = {0.f,0.f,0.f,0.f}, a1 = {0.f,0.f,0.f,0.f};
    if (nA < N){
      const float* ap = x + (size_t)nA * D + kc * 32 + g * 8;
      a0 = *(const float4*)ap; a1 = *(const float4*)(ap + 4);
    }
    bf16x8 af;
    af[0] = (short)f2bf(a0.x); af[1] = (short)f2bf(a0.y);
    af[2] = (short)f2bf(a0.z); af[3] = (short)f2bf(a0.w);
    af[4] = (short)f2bf(a1.x); af[5] = (short)f2bf(a1.y);
    af[6] = (short)f2bf(a1.z); af[7] = (short)f2bf(a1.w);
#pragma unroll
    for (int hf = 0; hf < 8; ++hf){
      bf16x8 bfr = *(const bf16x8*)&wt[hf * 16 + m16][kc * 32 + g * 8];
      acc[hf] = __builtin_amdgcn_mfma_f32_16x16x32_bf16(af, bfr, acc[hf], 0, 0, 0);
    }
  }
  // rows -> LDS (per-node bias added here; invalid rows zeroed)
#pragma unroll
  for (int hf = 0; hf < 8; ++hf){
    int h = hf * 16 + m16;
    float bv = lb[h];
#pragma unroll
    for (int jj = 0; jj < 4; ++jj){
      int row = wv * 16 + g * 4 + jj;
      int n = n0 + row;
      st[row][h] = (n < N) ? (acc[hf][jj] + bv) : 0.f;
    }
  }
  if (threadIdx.x < 64){
    int n = n0 + threadIdx.x;
    bsh[threadIdx.x] = (n < N) ? batch[n] : -1;
  }
  __syncthreads();
  // scan sorted rows, one atomic per (graph,h) run
  if (threadIdx.x < 128){
    int h = threadIdx.x;
    int lastValid = (N - n0 < 64) ? (N - n0 - 1) : 63;
    int cg = bsh[0];
    float sum = 0.f;
    for (int row = 0; row <= lastValid; ++row){
      int bg = bsh[row];
      if (bg != cg){
        atomicAdd(&out[(size_t)cg * D + h], sum);
        sum = 0.f; cg = bg;
      }
      sum += st[row][h];
    }
    atomicAdd(&out[(size_t)cg * D + h], sum);
  }
}

extern "C" void kernel_launch(void* const* d_in, const int* in_sizes, int n_in,
                              void* d_out, int out_size, void* d_ws, size_t ws_size,
                              hipStream_t stream){
  const int*   xpad  = (const int*)d_in[0];
  const int*   eidx  = (const int*)d_in[1];
  const int*   etyp  = (const int*)d_in[2];
  const int*   batch = (const int*)d_in[3];
  const float* emb   = (const float*)d_in[4];
  const float* w1    = (const float*)d_in[5];
  const float* q1    = (const float*)d_in[6];
  const float* k1    = (const float*)d_in[7];
  const float* b1    = (const float*)d_in[8];
  const float* w2    = (const float*)d_in[9];
  const float* q2    = (const float*)d_in[10];
  const float* k2    = (const float*)d_in[11];
  const float* b2    = (const float*)d_in[12];
  const float* lw    = (const float*)d_in[13];
  const float* lb    = (const float*)d_in[14];

  int N = in_sizes[3];
  int M = in_sizes[0] / N;
  int E = in_sizes[2];
  int R = in_sizes[5] / (128 * 128);
  int NB = N * R;
  const int* esrc = eidx;
  const int* edst = eidx + E;

  char* p = (char*)d_ws;
  auto carve = [&](size_t b) -> void* {
    void* q = (void*)p; p += (b + 255) & ~(size_t)255; return q;
  };
  float* x_a  = (float*)carve((size_t)N * D * 4);
  float* x_b  = (float*)carve((size_t)N * D * 4);
  float* wq1  = (float*)carve((size_t)R * D * 4);
  float* wk1  = (float*)carve((size_t)R * D * 4);
  float* wq2  = (float*)carve((size_t)R * D * 4);
  float* wk2  = (float*)carve((size_t)R * D * 4);
  float* aT   = (float*)carve((size_t)N * R * 4);
  float* bT   = (float*)carve((size_t)N * R * 4);
  int*   rp   = (int*)carve((size_t)(NB + 1) * 4);
  int*   cur  = (int*)carve((size_t)NB * 4);
  int*   pack = (int*)carve((size_t)E * 4);
  float* alp  = (float*)carve((size_t)E * 4);
  unsigned short* wbf1 = (unsigned short*)carve((size_t)R * 128 * 128 * 2);
  unsigned short* wbf2 = (unsigned short*)carve((size_t)R * 128 * 128 * 2);
  unsigned short* lwbf = (unsigned short*)carve((size_t)128 * 128 * 2);
  int* bsum = (int*)carve((size_t)4096 * 4);
  int* boff = (int*)carve((size_t)4096 * 4);
  if ((size_t)(p - (char*)d_ws) > ws_size) return;  // base ws too small: fail visibly
  unsigned short* xw = (unsigned short*)carve((size_t)N * R * 128 * 2);
  bool use_xw = ((size_t)(p - (char*)d_ws) <= ws_size);

  hipMemsetAsync(cur, 0, (size_t)NB * 4, stream);
  hipMemsetAsync(d_out, 0, (size_t)out_size * 4, stream);

  int eg = (E + 255) / 256;
  int nblk = (NB + 1023) / 1024;
  k_count   <<<eg, 256, 0, stream>>>(edst, etyp, cur, E, R);
  k_scan_blk<<<nblk, 256, 0, stream>>>(cur, bsum, NB);
  k_scan_top<<<1, 1024, 0, stream>>>(bsum, boff, rp, nblk, NB);
  k_scan_fin<<<nblk, 256, 0, stream>>>(cur, boff, rp, NB);
  k_scatter <<<eg, 256, 0, stream>>>(esrc, edst, etyp, cur, pack, E, R);

  k_wqk<<<(R * D + 255) / 256, 256, 0, stream>>>(w1, q1, k1, wq1, wk1, R * D);
  k_wqk<<<(R * D + 255) / 256, 256, 0, stream>>>(w2, q2, k2, wq2, wk2, R * D);
  int wtot = R * 128 * 128;
  k_wtr<<<(wtot + 255) / 256, 256, 0, stream>>>(w1, wbf1, wtot);
  k_wtr<<<(wtot + 255) / 256, 256, 0, stream>>>(w2, wbf2, wtot);
  k_cvt<<<(128 * 128 + 255) / 256, 256, 0, stream>>>(lw, lwbf, 128 * 128);

  int ng4 = (N + 3) / 4;
  int ntile = (N + 63) / 64;
  k_pool<<<ng4, 256, 0, stream>>>(xpad, emb, x_a, N, M);

  // layer 1
  k_ab   <<<ng4, 256, 0, stream>>>(x_a, wq1, wk1, aT, bT, N, R);
  k_alpha<<<ng4, 256, 0, stream>>>(rp, pack, aT, bT, alp, N, R);
  if (use_xw){
    k_xw  <<<ntile, 256, 0, stream>>>(x_a, wbf1, xw, N, R);
    k_aggX<<<ng4, 256, 0, stream>>>(xw, rp, pack, alp, b1, x_b, N, R);
  } else {
    k_agg <<<ntile, 256, 0, stream>>>(x_a, wbf1, b1, rp, pack, alp, x_b, N, R);
  }

  // layer 2
  k_ab   <<<ng4, 256, 0, stream>>>(x_b, wq2, wk2, aT, bT, N, R);
  k_alpha<<<ng4, 256, 0, stream>>>(rp, pack, aT, bT, alp, N, R);
  if (use_xw){
    k_xw  <<<ntile, 256, 0, stream>>>(x_b, wbf2, xw, N, R);
    k_aggX<<<ng4, 256, 0, stream>>>(xw, rp, pack, alp, b2, x_a, N, R);
  } else {
    k_agg <<<ntile, 256, 0, stream>>>(x_b, wbf2, b2, rp, pack, alp, x_a, N, R);
  }

  // final linear + graph segment-sum
  k_final<<<ntile, 256, 0, stream>>>(x_a, lwbf, lb, batch, (float*)d_out, N);
}

// Round 7
// 643.370 us; speedup vs baseline: 3.4761x; 1.0562x over previous
//
#include <hip/hip_runtime.h>
#include <hip/hip_bf16.h>
#include <math.h>

#define D 128

typedef __attribute__((ext_vector_type(4))) float f32x4;
typedef __attribute__((ext_vector_type(8))) short bf16x8;

__device__ inline unsigned short f2bf(float f){
  unsigned u = __float_as_uint(f);
  u += 0x7fffu + ((u >> 16) & 1u);
  return (unsigned short)(u >> 16);
}
__device__ inline float wred_sum(float v){
#pragma unroll
  for (int m = 1; m < 64; m <<= 1) v += __shfl_xor(v, m, 64);
  return v;
}
__device__ inline float wred_max(float v){
#pragma unroll
  for (int m = 1; m < 64; m <<= 1) v = fmaxf(v, __shfl_xor(v, m, 64));
  return v;
}

// ---- embedding mean-pool: wave per node; padding is suffix-only ----
__global__ __launch_bounds__(256) void k_pool(const int* __restrict__ xpad,
    const float* __restrict__ emb, float* __restrict__ xo, int N, int M){
  int wv = threadIdx.x >> 6, ln = threadIdx.x & 63;
  int n = blockIdx.x * 4 + wv;
  if (n >= N) return;
  int cnt = 0;
  while (cnt < M && xpad[n * M + cnt] >= 0) ++cnt;
  float2 acc = {0.f, 0.f};
  int m = 0;
  for (; m + 1 < cnt; m += 2){
    int i0 = xpad[n * M + m], i1 = xpad[n * M + m + 1];
    float2 v0 = ((const float2*)(emb + (size_t)i0 * D))[ln];
    float2 v1 = ((const float2*)(emb + (size_t)i1 * D))[ln];
    acc.x += v0.x + v1.x; acc.y += v0.y + v1.y;
  }
  if (m < cnt){
    int i0 = xpad[n * M + m];
    float2 v0 = ((const float2*)(emb + (size_t)i0 * D))[ln];
    acc.x += v0.x; acc.y += v0.y;
  }
  float inv = 1.f / (float)cnt;
  float2 o; o.x = acc.x * inv; o.y = acc.y * inv;
  ((float2*)(xo + (size_t)n * D))[ln] = o;
}

// ---- CSR build over buckets (dst*R + et) ----
__global__ void k_count(const int* __restrict__ dst, const int* __restrict__ et,
                        int* __restrict__ cnt, int E, int R){
  int e = blockIdx.x * 256 + threadIdx.x;
  if (e < E) atomicAdd(&cnt[dst[e] * R + et[e]], 1);
}

// ---- hierarchical exclusive scan over nb buckets (1024 elems / block) ----
__global__ __launch_bounds__(256) void k_scan_blk(const int* __restrict__ cc,
    int* __restrict__ bsum, int nb){
  __shared__ int sh[256];
  int base = blockIdx.x * 1024 + threadIdx.x * 4;
  int s = 0;
#pragma unroll
  for (int j = 0; j < 4; ++j){
    int i = base + j;
    if (i < nb) s += cc[i];
  }
  sh[threadIdx.x] = s; __syncthreads();
  for (int off = 128; off > 0; off >>= 1){
    if (threadIdx.x < off) sh[threadIdx.x] += sh[threadIdx.x + off];
    __syncthreads();
  }
  if (threadIdx.x == 0) bsum[blockIdx.x] = sh[0];
}

__global__ __launch_bounds__(1024) void k_scan_top(const int* __restrict__ bsum,
    int* __restrict__ boff, int* __restrict__ rp, int nblk, int nb){
  __shared__ int sh[1024];
  int t = threadIdx.x;
  int v = (t < nblk) ? bsum[t] : 0;
  sh[t] = v; __syncthreads();
  for (int off = 1; off < 1024; off <<= 1){
    int a = sh[t];
    int b = (t >= off) ? sh[t - off] : 0;
    __syncthreads();
    sh[t] = a + b;
    __syncthreads();
  }
  if (t < nblk) boff[t] = sh[t] - v;       // exclusive
  if (t == 1023) rp[nb] = sh[1023];        // total
}

__global__ __launch_bounds__(256) void k_scan_fin(int* __restrict__ cc,
    const int* __restrict__ boff, int* __restrict__ rp, int nb){
  __shared__ int sh[256];
  int t = threadIdx.x;
  int base = blockIdx.x * 1024 + t * 4;
  int c[4]; int local = 0;
#pragma unroll
  for (int j = 0; j < 4; ++j){
    int i = base + j;
    c[j] = (i < nb) ? cc[i] : 0;
    local += c[j];
  }
  sh[t] = local; __syncthreads();
  for (int off = 1; off < 256; off <<= 1){
    int a = sh[t];
    int b = (t >= off) ? sh[t - off] : 0;
    __syncthreads();
    sh[t] = a + b;
    __syncthreads();
  }
  int run = sh[t] - local + boff[blockIdx.x];
#pragma unroll
  for (int j = 0; j < 4; ++j){
    int i = base + j;
    if (i < nb){ rp[i] = run; cc[i] = run; run += c[j]; }
  }
}

__global__ void k_scatter(const int* __restrict__ src, const int* __restrict__ dst,
    const int* __restrict__ et, int* __restrict__ cur, int* __restrict__ pack, int E, int R){
  int e = blockIdx.x * 256 + threadIdx.x;
  if (e < E){
    int t = et[e];
    int p = atomicAdd(&cur[dst[e] * R + t], 1);
    pack[p] = (t << 27) | src[e];
  }
}

// ---- wq[r][d] = sum_h w[r][d][h]*q[h]; wk likewise ----
__global__ void k_wqk(const float* __restrict__ w, const float* __restrict__ q,
    const float* __restrict__ kk, float* __restrict__ wq, float* __restrict__ wk, int RD){
  int id = blockIdx.x * 256 + threadIdx.x;
  if (id >= RD) return;
  const float* wr = w + (size_t)id * D;
  float sq = 0.f, sk = 0.f;
  for (int h = 0; h < D; ++h){ float v = wr[h]; sq += v * q[h]; sk += v * kk[h]; }
  wq[id] = sq; wk[id] = sk;
}

// ---- w[r][d][h] fp32 -> wbf[r][h][d] bf16 (transposed) ----
__global__ void k_wtr(const float* __restrict__ w, unsigned short* __restrict__ wbf, int total){
  int id = blockIdx.x * 256 + threadIdx.x;
  if (id >= total) return;
  int d = id & 127, h = (id >> 7) & 127, r = id >> 14;
  wbf[id] = f2bf(w[(size_t)r * 16384 + d * 128 + h]);
}

// ---- plain fp32 -> bf16 convert (no transpose) ----
__global__ void k_cvt(const float* __restrict__ s, unsigned short* __restrict__ dd, int total){
  int id = blockIdx.x * 256 + threadIdx.x;
  if (id < total) dd[id] = f2bf(s[id]);
}

// ---- a[n,r]=x[n].wq[r], b[n,r]=x[n].wk[r]: wave per node ----
__global__ __launch_bounds__(256) void k_ab(const float* __restrict__ x,
    const float* __restrict__ wq, const float* __restrict__ wk,
    float* __restrict__ aT, float* __restrict__ bT, int N, int R){
  __shared__ float lq[8 * D], lk[8 * D];
  for (int i = threadIdx.x; i < R * D; i += 256){ lq[i] = wq[i]; lk[i] = wk[i]; }
  __syncthreads();
  int wv = threadIdx.x >> 6, ln = threadIdx.x & 63;
  int n = blockIdx.x * 4 + wv;
  if (n >= N) return;
  float2 xv = ((const float2*)(x + (size_t)n * D))[ln];
  for (int r = 0; r < R; ++r){
    float pa = xv.x * lq[r * D + 2 * ln] + xv.y * lq[r * D + 2 * ln + 1];
    float pb = xv.x * lk[r * D + 2 * ln] + xv.y * lk[r * D + 2 * ln + 1];
    pa = wred_sum(pa); pb = wred_sum(pb);
    if (ln == 0){ aT[n * R + r] = pa; bT[n * R + r] = pb; }
  }
}

// ---- segment softmax over dst: wave per node ----
__global__ __launch_bounds__(256) void k_alpha(const int* __restrict__ rp,
    const int* __restrict__ pack, const float* __restrict__ aT, const float* __restrict__ bT,
    float* __restrict__ alp, int N, int R){
  int wv = threadIdx.x >> 6, ln = threadIdx.x & 63;
  int n = blockIdx.x * 4 + wv;
  if (n >= N) return;
  int beg = rp[n * R], end = rp[n * R + R];
  if (end <= beg) return;
  float mx = -3.4e38f;
  for (int i = beg + ln; i < end; i += 64){
    int v = pack[i]; int t = v >> 27; int s = v & 0x7ffffff;
    float l = aT[n * R + t] + bT[s * R + t];
    l = l > 0.f ? l : 0.2f * l;
    mx = fmaxf(mx, l);
  }
  mx = wred_max(mx);
  float sm = 0.f;
  for (int i = beg + ln; i < end; i += 64){
    int v = pack[i]; int t = v >> 27; int s = v & 0x7ffffff;
    float l = aT[n * R + t] + bT[s * R + t];
    l = l > 0.f ? l : 0.2f * l;
    float ev = __expf(l - mx);
    alp[i] = ev; sm += ev;
  }
  sm = wred_sum(sm);
  float inv = 1.f / sm;
  for (int i = beg + ln; i < end; i += 64) alp[i] *= inv;
}

// ---- xw[n][r*128+h] = (x[n] @ w[r])[h], bf16, via MFMA.
//      ONE (tile, r) PER BLOCK: no serial r-loop, no loop-carried barrier
//      drain; grid = ntile*R gives ~25k waves of independent work. ----
__global__ __launch_bounds__(256) void k_xw(const float* __restrict__ x,
    const unsigned short* __restrict__ wbf,  // [R][h][k] bf16
    unsigned short* __restrict__ xw,         // [N][R*128] bf16
    int N, int R){
  __shared__ unsigned short ot[64][136];     // 272B rows (17x16B): uint4-aligned
  int wv = threadIdx.x >> 6, ln = threadIdx.x & 63;
  int g = ln >> 4, m16 = ln & 15;
  int r    = blockIdx.x % R;                 // consecutive blocks share the x tile
  int tile = blockIdx.x / R;
  int n0 = tile * 64;
  int nA = n0 + wv * 16 + m16;
  bf16x8 af[4];
#pragma unroll
  for (int kc = 0; kc < 4; ++kc){
    float4 a0 = {0.f,0.f,0.f,0.f}, a1 = {0.f,0.f,0.f,0.f};
    if (nA < N){
      const float* ap = x + (size_t)nA * D + kc * 32 + g * 8;
      a0 = *(const float4*)ap; a1 = *(const float4*)(ap + 4);
    }
    af[kc][0] = (short)f2bf(a0.x); af[kc][1] = (short)f2bf(a0.y);
    af[kc][2] = (short)f2bf(a0.z); af[kc][3] = (short)f2bf(a0.w);
    af[kc][4] = (short)f2bf(a1.x); af[kc][5] = (short)f2bf(a1.y);
    af[kc][6] = (short)f2bf(a1.z); af[kc][7] = (short)f2bf(a1.w);
  }
  int RD128 = R * 128;
  f32x4 acc[8];
#pragma unroll
  for (int i = 0; i < 8; ++i) acc[i] = (f32x4){0.f, 0.f, 0.f, 0.f};
  const unsigned short* wr = wbf + (size_t)r * 16384;
#pragma unroll
  for (int kc = 0; kc < 4; ++kc){
#pragma unroll
    for (int hf = 0; hf < 8; ++hf){
      bf16x8 bfr = *(const bf16x8*)(wr + (hf * 16 + m16) * 128 + kc * 32 + g * 8);
      acc[hf] = __builtin_amdgcn_mfma_f32_16x16x32_bf16(af[kc], bfr, acc[hf], 0, 0, 0);
    }
  }
#pragma unroll
  for (int hf = 0; hf < 8; ++hf){
#pragma unroll
    for (int jj = 0; jj < 4; ++jj){
      ot[wv * 16 + g * 4 + jj][hf * 16 + m16] = f2bf(acc[hf][jj]);
    }
  }
  __syncthreads();
  // cooperative coalesced write: 1024 x uint4 (16 lanes cover 256B of a row)
  for (int i = threadIdx.x; i < 1024; i += 256){
    int row = i >> 4, c16 = i & 15;
    int n = n0 + row;
    if (n < N)
      *(uint4*)(xw + (size_t)n * RD128 + r * 128 + c16 * 8) = *(const uint4*)&ot[row][c16 * 8];
  }
}

// ---- aggregation: one wave per node, 4-wide edge unroll for MLP ----
__global__ __launch_bounds__(256) void k_aggX(const unsigned short* __restrict__ xw,
    const int* __restrict__ rp, const int* __restrict__ pack, const float* __restrict__ alp,
    const float* __restrict__ bias, float* __restrict__ xo, int N, int R){
  int wv = threadIdx.x >> 6, ln = threadIdx.x & 63;
  int n = blockIdx.x * 4 + wv;
  if (n >= N) return;
  int beg = rp[n * R], end = rp[n * R + R];
  int RD128 = R * 128;
  float2 s0 = {0.f, 0.f}, s1 = {0.f, 0.f}, s2 = {0.f, 0.f}, s3 = {0.f, 0.f};
  int i = beg;
  for (; i + 3 < end; i += 4){
    int v0 = pack[i], v1 = pack[i + 1], v2 = pack[i + 2], v3 = pack[i + 3];
    float al0 = alp[i], al1 = alp[i + 1], al2 = alp[i + 2], al3 = alp[i + 3];
    unsigned u0 = *(const unsigned*)(xw + (size_t)(v0 & 0x7ffffff) * RD128 + (v0 >> 27) * 128 + 2 * ln);
    unsigned u1 = *(const unsigned*)(xw + (size_t)(v1 & 0x7ffffff) * RD128 + (v1 >> 27) * 128 + 2 * ln);
    unsigned u2 = *(const unsigned*)(xw + (size_t)(v2 & 0x7ffffff) * RD128 + (v2 >> 27) * 128 + 2 * ln);
    unsigned u3 = *(const unsigned*)(xw + (size_t)(v3 & 0x7ffffff) * RD128 + (v3 >> 27) * 128 + 2 * ln);
    s0.x += al0 * __uint_as_float(u0 << 16);
    s0.y += al0 * __uint_as_float(u0 & 0xffff0000u);
    s1.x += al1 * __uint_as_float(u1 << 16);
    s1.y += al1 * __uint_as_float(u1 & 0xffff0000u);
    s2.x += al2 * __uint_as_float(u2 << 16);
    s2.y += al2 * __uint_as_float(u2 & 0xffff0000u);
    s3.x += al3 * __uint_as_float(u3 << 16);
    s3.y += al3 * __uint_as_float(u3 & 0xffff0000u);
  }
  for (; i < end; ++i){
    int v0 = pack[i];
    float al0 = alp[i];
    unsigned u0 = *(const unsigned*)(xw + (size_t)(v0 & 0x7ffffff) * RD128 + (v0 >> 27) * 128 + 2 * ln);
    s0.x += al0 * __uint_as_float(u0 << 16);
    s0.y += al0 * __uint_as_float(u0 & 0xffff0000u);
  }
  float2 o;
  o.x = fmaxf(s0.x + s1.x + s2.x + s3.x + bias[2 * ln], 0.f);
  o.y = fmaxf(s0.y + s1.y + s2.y + s3.y + bias[2 * ln + 1], 0.f);
  ((float2*)(xo + (size_t)n * D))[ln] = o;
}

// ---- fallback: fused aggregate (S-tile in LDS) + MFMA GEMM + bias + relu ----
__global__ __launch_bounds__(256) void k_agg(const float* __restrict__ x_in,
    const unsigned short* __restrict__ wbf, const float* __restrict__ bias,
    const int* __restrict__ rp, const int* __restrict__ pack,
    const float* __restrict__ alp, float* __restrict__ x_out, int N, int R){
  __shared__ float st[64][132];
  __shared__ unsigned short wt[128][136];
  int wv = threadIdx.x >> 6, ln = threadIdx.x & 63;
  int g = ln >> 4, m16 = ln & 15;
  int n0 = blockIdx.x * 64;
  f32x4 acc[8];
#pragma unroll
  for (int i = 0; i < 8; ++i) acc[i] = (f32x4){0.f, 0.f, 0.f, 0.f};

  for (int r = 0; r < R; ++r){
    __syncthreads();
    {
      const uint4* src = (const uint4*)(wbf + (size_t)r * 16384);
      for (int i = threadIdx.x; i < 2048; i += 256){
        int h = i >> 4, dblk = i & 15;
        *(uint4*)&wt[h][dblk * 8] = src[i];
      }
    }
    for (int j = 0; j < 16; ++j){
      int n = n0 + wv * 16 + j;
      float2 s2 = {0.f, 0.f};
      if (n < N){
        int beg = rp[n * R + r], end = rp[n * R + r + 1];
        for (int i = beg; i < end; ++i){
          int s = pack[i] & 0x7ffffff;
          float al = alp[i];
          float2 xv = ((const float2*)(x_in + (size_t)s * D))[ln];
          s2.x += al * xv.x; s2.y += al * xv.y;
        }
      }
      *(float2*)&st[wv * 16 + j][2 * ln] = s2;
    }
    __syncthreads();
#pragma unroll
    for (int kc = 0; kc < 4; ++kc){
      const float* ap = &st[wv * 16 + m16][kc * 32 + g * 8];
      float4 a0 = *(const float4*)ap;
      float4 a1 = *(const float4*)(ap + 4);
      bf16x8 af;
      af[0] = (short)f2bf(a0.x); af[1] = (short)f2bf(a0.y);
      af[2] = (short)f2bf(a0.z); af[3] = (short)f2bf(a0.w);
      af[4] = (short)f2bf(a1.x); af[5] = (short)f2bf(a1.y);
      af[6] = (short)f2bf(a1.z); af[7] = (short)f2bf(a1.w);
#pragma unroll
      for (int hf = 0; hf < 8; ++hf){
        bf16x8 bfr = *(const bf16x8*)&wt[hf * 16 + m16][kc * 32 + g * 8];
        acc[hf] = __builtin_amdgcn_mfma_f32_16x16x32_bf16(af, bfr, acc[hf], 0, 0, 0);
      }
    }
  }
#pragma unroll
  for (int hf = 0; hf < 8; ++hf){
    int h = hf * 16 + m16;
    float bv = bias[h];
#pragma unroll
    for (int jj = 0; jj < 4; ++jj){
      int n = n0 + wv * 16 + g * 4 + jj;
      if (n < N){
        float v = acc[hf][jj] + bv;
        x_out[(size_t)n * D + h] = fmaxf(v, 0.f);
      }
    }
  }
}

// ---- final linear + per-graph segment sum: LDS per-block reduce over sorted
// batch runs, then ONE atomicAdd per (graph,h) run present in the tile ----
__global__ __launch_bounds__(256) void k_final(const float* __restrict__ x,
    const unsigned short* __restrict__ lwbf, const float* __restrict__ lb,
    const int* __restrict__ batch, float* __restrict__ out, int N){
  __shared__ unsigned short wt[128][136]; // lin_w [h][k] bf16
  __shared__ float st[64][129];           // per-node output rows
  __shared__ int bsh[64];
  {
    const uint4* src = (const uint4*)lwbf;
    for (int i = threadIdx.x; i < 2048; i += 256){
      int h = i >> 4, kblk = i & 15;
      *(uint4*)&wt[h][kblk * 8] = src[i];
    }
  }
  __syncthreads();
  int wv = threadIdx.x >> 6, ln = threadIdx.x & 63;
  int g = ln >> 4, m16 = ln & 15;
  int n0 = blockIdx.x * 64;
  f32x4 acc[8];
#pragma unroll
  for (int i = 0; i < 8; ++i) acc[i] = (f32x4){0.f, 0.f, 0.f, 0.f};
#pragma unroll
  for (int kc = 0; kc < 4; ++kc){
    int nA = n0 + wv * 16 + m16;
    float4 a0 = {0.f,0.f,0.f,0.f}, a1 = {0.f,0.f,0.f,0.f};
    if (nA < N){
      const float* ap = x + (size_t)nA * D + kc * 32 + g * 8;
      a0 = *(const float4*)ap; a1 = *(const float4*)(ap + 4);
    }
    bf16x8 af;
    af[0] = (short)f2bf(a0.x); af[1] = (short)f2bf(a0.y);
    af[2] = (short)f2bf(a0.z); af[3] = (short)f2bf(a0.w);
    af[4] = (short)f2bf(a1.x); af[5] = (short)f2bf(a1.y);
    af[6] = (short)f2bf(a1.z); af[7] = (short)f2bf(a1.w);
#pragma unroll
    for (int hf = 0; hf < 8; ++hf){
      bf16x8 bfr = *(const bf16x8*)&wt[hf * 16 + m16][kc * 32 + g * 8];
      acc[hf] = __builtin_amdgcn_mfma_f32_16x16x32_bf16(af, bfr, acc[hf], 0, 0, 0);
    }
  }
  // rows -> LDS (per-node bias added here; invalid rows zeroed)
#pragma unroll
  for (int hf = 0; hf < 8; ++hf){
    int h = hf * 16 + m16;
    float bv = lb[h];
#pragma unroll
    for (int jj = 0; jj < 4; ++jj){
      int row = wv * 16 + g * 4 + jj;
      int n = n0 + row;
      st[row][h] = (n < N) ? (acc[hf][jj] + bv) : 0.f;
    }
  }
  if (threadIdx.x < 64){
    int n = n0 + threadIdx.x;
    bsh[threadIdx.x] = (n < N) ? batch[n] : -1;
  }
  __syncthreads();
  // scan sorted rows, one atomic per (graph,h) run
  if (threadIdx.x < 128){
    int h = threadIdx.x;
    int lastValid = (N - n0 < 64) ? (N - n0 - 1) : 63;
    int cg = bsh[0];
    float sum = 0.f;
    for (int row = 0; row <= lastValid; ++row){
      int bg = bsh[row];
      if (bg != cg){
        atomicAdd(&out[(size_t)cg * D + h], sum);
        sum = 0.f; cg = bg;
      }
      sum += st[row][h];
    }
    atomicAdd(&out[(size_t)cg * D + h], sum);
  }
}

extern "C" void kernel_launch(void* const* d_in, const int* in_sizes, int n_in,
                              void* d_out, int out_size, void* d_ws, size_t ws_size,
                              hipStream_t stream){
  const int*   xpad  = (const int*)d_in[0];
  const int*   eidx  = (const int*)d_in[1];
  const int*   etyp  = (const int*)d_in[2];
  const int*   batch = (const int*)d_in[3];
  const float* emb   = (const float*)d_in[4];
  const float* w1    = (const float*)d_in[5];
  const float* q1    = (const float*)d_in[6];
  const float* k1    = (const float*)d_in[7];
  const float* b1    = (const float*)d_in[8];
  const float* w2    = (const float*)d_in[9];
  const float* q2    = (const float*)d_in[10];
  const float* k2    = (const float*)d_in[11];
  const float* b2    = (const float*)d_in[12];
  const float* lw    = (const float*)d_in[13];
  const float* lb    = (const float*)d_in[14];

  int N = in_sizes[3];
  int M = in_sizes[0] / N;
  int E = in_sizes[2];
  int R = in_sizes[5] / (128 * 128);
  int NB = N * R;
  const int* esrc = eidx;
  const int* edst = eidx + E;

  char* p = (char*)d_ws;
  auto carve = [&](size_t b) -> void* {
    void* q = (void*)p; p += (b + 255) & ~(size_t)255; return q;
  };
  float* x_a  = (float*)carve((size_t)N * D * 4);
  float* x_b  = (float*)carve((size_t)N * D * 4);
  float* wq1  = (float*)carve((size_t)R * D * 4);
  float* wk1  = (float*)carve((size_t)R * D * 4);
  float* wq2  = (float*)carve((size_t)R * D * 4);
  float* wk2  = (float*)carve((size_t)R * D * 4);
  float* aT   = (float*)carve((size_t)N * R * 4);
  float* bT   = (float*)carve((size_t)N * R * 4);
  int*   rp   = (int*)carve((size_t)(NB + 1) * 4);
  int*   cur  = (int*)carve((size_t)NB * 4);
  int*   pack = (int*)carve((size_t)E * 4);
  float* alp  = (float*)carve((size_t)E * 4);
  unsigned short* wbf1 = (unsigned short*)carve((size_t)R * 128 * 128 * 2);
  unsigned short* wbf2 = (unsigned short*)carve((size_t)R * 128 * 128 * 2);
  unsigned short* lwbf = (unsigned short*)carve((size_t)128 * 128 * 2);
  int* bsum = (int*)carve((size_t)4096 * 4);
  int* boff = (int*)carve((size_t)4096 * 4);
  if ((size_t)(p - (char*)d_ws) > ws_size) return;  // base ws too small: fail visibly
  unsigned short* xw = (unsigned short*)carve((size_t)N * R * 128 * 2);
  bool use_xw = ((size_t)(p - (char*)d_ws) <= ws_size);

  hipMemsetAsync(cur, 0, (size_t)NB * 4, stream);
  hipMemsetAsync(d_out, 0, (size_t)out_size * 4, stream);

  int eg = (E + 255) / 256;
  int nblk = (NB + 1023) / 1024;
  k_count   <<<eg, 256, 0, stream>>>(edst, etyp, cur, E, R);
  k_scan_blk<<<nblk, 256, 0, stream>>>(cur, bsum, NB);
  k_scan_top<<<1, 1024, 0, stream>>>(bsum, boff, rp, nblk, NB);
  k_scan_fin<<<nblk, 256, 0, stream>>>(cur, boff, rp, NB);
  k_scatter <<<eg, 256, 0, stream>>>(esrc, edst, etyp, cur, pack, E, R);

  k_wqk<<<(R * D + 255) / 256, 256, 0, stream>>>(w1, q1, k1, wq1, wk1, R * D);
  k_wqk<<<(R * D + 255) / 256, 256, 0, stream>>>(w2, q2, k2, wq2, wk2, R * D);
  int wtot = R * 128 * 128;
  k_wtr<<<(wtot + 255) / 256, 256, 0, stream>>>(w1, wbf1, wtot);
  k_wtr<<<(wtot + 255) / 256, 256, 0, stream>>>(w2, wbf2, wtot);
  k_cvt<<<(128 * 128 + 255) / 256, 256, 0, stream>>>(lw, lwbf, 128 * 128);

  int ng4 = (N + 3) / 4;
  int ntile = (N + 63) / 64;
  k_pool<<<ng4, 256, 0, stream>>>(xpad, emb, x_a, N, M);

  // layer 1
  k_ab   <<<ng4, 256, 0, stream>>>(x_a, wq1, wk1, aT, bT, N, R);
  k_alpha<<<ng4, 256, 0, stream>>>(rp, pack, aT, bT, alp, N, R);
  if (use_xw){
    k_xw  <<<ntile * R, 256, 0, stream>>>(x_a, wbf1, xw, N, R);
    k_aggX<<<ng4, 256, 0, stream>>>(xw, rp, pack, alp, b1, x_b, N, R);
  } else {
    k_agg <<<ntile, 256, 0, stream>>>(x_a, wbf1, b1, rp, pack, alp, x_b, N, R);
  }

  // layer 2
  k_ab   <<<ng4, 256, 0, stream>>>(x_b, wq2, wk2, aT, bT, N, R);
  k_alpha<<<ng4, 256, 0, stream>>>(rp, pack, aT, bT, alp, N, R);
  if (use_xw){
    k_xw  <<<ntile * R, 256, 0, stream>>>(x_b, wbf2, xw, N, R);
    k_aggX<<<ng4, 256, 0, stream>>>(xw, rp, pack, alp, b2, x_a, N, R);
  } else {
    k_agg <<<ntile, 256, 0, stream>>>(x_b, wbf2, b2, rp, pack, alp, x_a, N, R);
  }

  // final linear + graph segment-sum
  k_final<<<ntile, 256, 0, stream>>>(x_a, lwbf, lb, batch, (float*)d_out, N);
}

// Round 8
// 638.733 us; speedup vs baseline: 3.5014x; 1.0073x over previous
//
#include <hip/hip_runtime.h>
#include <hip/hip_bf16.h>
#include <math.h>

#define D 128

typedef __attribute__((ext_vector_type(4))) float f32x4;
typedef __attribute__((ext_vector_type(8))) short bf16x8;

__device__ inline unsigned short f2bf(float f){
  unsigned u = __float_as_uint(f);
  u += 0x7fffu + ((u >> 16) & 1u);
  return (unsigned short)(u >> 16);
}
__device__ inline float wred_sum(float v){
#pragma unroll
  for (int m = 1; m < 64; m <<= 1) v += __shfl_xor(v, m, 64);
  return v;
}
__device__ inline float wred_max(float v){
#pragma unroll
  for (int m = 1; m < 64; m <<= 1) v = fmaxf(v, __shfl_xor(v, m, 64));
  return v;
}

// ---- embedding mean-pool: wave per node; padding is suffix-only ----
__global__ __launch_bounds__(256) void k_pool(const int* __restrict__ xpad,
    const float* __restrict__ emb, float* __restrict__ xo, int N, int M){
  int wv = threadIdx.x >> 6, ln = threadIdx.x & 63;
  int n = blockIdx.x * 4 + wv;
  if (n >= N) return;
  int cnt = 0;
  while (cnt < M && xpad[n * M + cnt] >= 0) ++cnt;
  float2 acc = {0.f, 0.f};
  int m = 0;
  for (; m + 1 < cnt; m += 2){
    int i0 = xpad[n * M + m], i1 = xpad[n * M + m + 1];
    float2 v0 = ((const float2*)(emb + (size_t)i0 * D))[ln];
    float2 v1 = ((const float2*)(emb + (size_t)i1 * D))[ln];
    acc.x += v0.x + v1.x; acc.y += v0.y + v1.y;
  }
  if (m < cnt){
    int i0 = xpad[n * M + m];
    float2 v0 = ((const float2*)(emb + (size_t)i0 * D))[ln];
    acc.x += v0.x; acc.y += v0.y;
  }
  float inv = 1.f / (float)cnt;
  float2 o; o.x = acc.x * inv; o.y = acc.y * inv;
  ((float2*)(xo + (size_t)n * D))[ln] = o;
}

// ---- CSR build over buckets (dst*R + et) ----
__global__ void k_count(const int* __restrict__ dst, const int* __restrict__ et,
                        int* __restrict__ cnt, int E, int R){
  int e = blockIdx.x * 256 + threadIdx.x;
  if (e < E) atomicAdd(&cnt[dst[e] * R + et[e]], 1);
}

// ---- hierarchical exclusive scan over nb buckets (1024 elems / block) ----
__global__ __launch_bounds__(256) void k_scan_blk(const int* __restrict__ cc,
    int* __restrict__ bsum, int nb){
  __shared__ int sh[256];
  int base = blockIdx.x * 1024 + threadIdx.x * 4;
  int s = 0;
#pragma unroll
  for (int j = 0; j < 4; ++j){
    int i = base + j;
    if (i < nb) s += cc[i];
  }
  sh[threadIdx.x] = s; __syncthreads();
  for (int off = 128; off > 0; off >>= 1){
    if (threadIdx.x < off) sh[threadIdx.x] += sh[threadIdx.x + off];
    __syncthreads();
  }
  if (threadIdx.x == 0) bsum[blockIdx.x] = sh[0];
}

__global__ __launch_bounds__(1024) void k_scan_top(const int* __restrict__ bsum,
    int* __restrict__ boff, int* __restrict__ rp, int nblk, int nb){
  __shared__ int sh[1024];
  int t = threadIdx.x;
  int v = (t < nblk) ? bsum[t] : 0;
  sh[t] = v; __syncthreads();
  for (int off = 1; off < 1024; off <<= 1){
    int a = sh[t];
    int b = (t >= off) ? sh[t - off] : 0;
    __syncthreads();
    sh[t] = a + b;
    __syncthreads();
  }
  if (t < nblk) boff[t] = sh[t] - v;       // exclusive
  if (t == 1023) rp[nb] = sh[1023];        // total
}

__global__ __launch_bounds__(256) void k_scan_fin(int* __restrict__ cc,
    const int* __restrict__ boff, int* __restrict__ rp, int nb){
  __shared__ int sh[256];
  int t = threadIdx.x;
  int base = blockIdx.x * 1024 + t * 4;
  int c[4]; int local = 0;
#pragma unroll
  for (int j = 0; j < 4; ++j){
    int i = base + j;
    c[j] = (i < nb) ? cc[i] : 0;
    local += c[j];
  }
  sh[t] = local; __syncthreads();
  for (int off = 1; off < 256; off <<= 1){
    int a = sh[t];
    int b = (t >= off) ? sh[t - off] : 0;
    __syncthreads();
    sh[t] = a + b;
    __syncthreads();
  }
  int run = sh[t] - local + boff[blockIdx.x];
#pragma unroll
  for (int j = 0; j < 4; ++j){
    int i = base + j;
    if (i < nb){ rp[i] = run; cc[i] = run; run += c[j]; }
  }
}

__global__ void k_scatter(const int* __restrict__ src, const int* __restrict__ dst,
    const int* __restrict__ et, int* __restrict__ cur, int* __restrict__ pack, int E, int R){
  int e = blockIdx.x * 256 + threadIdx.x;
  if (e < E){
    int t = et[e];
    int p = atomicAdd(&cur[dst[e] * R + t], 1);
    pack[p] = (t << 27) | src[e];
  }
}

// ---- wq[r][d] = sum_h w[r][d][h]*q[h]; wk likewise ----
__global__ void k_wqk(const float* __restrict__ w, const float* __restrict__ q,
    const float* __restrict__ kk, float* __restrict__ wq, float* __restrict__ wk, int RD){
  int id = blockIdx.x * 256 + threadIdx.x;
  if (id >= RD) return;
  const float* wr = w + (size_t)id * D;
  float sq = 0.f, sk = 0.f;
  for (int h = 0; h < D; ++h){ float v = wr[h]; sq += v * q[h]; sk += v * kk[h]; }
  wq[id] = sq; wk[id] = sk;
}

// ---- w[r][d][h] fp32 -> wbf[r][h][d] bf16 (transposed) ----
__global__ void k_wtr(const float* __restrict__ w, unsigned short* __restrict__ wbf, int total){
  int id = blockIdx.x * 256 + threadIdx.x;
  if (id >= total) return;
  int d = id & 127, h = (id >> 7) & 127, r = id >> 14;
  wbf[id] = f2bf(w[(size_t)r * 16384 + d * 128 + h]);
}

// ---- plain fp32 -> bf16 convert (no transpose) ----
__global__ void k_cvt(const float* __restrict__ s, unsigned short* __restrict__ dd, int total){
  int id = blockIdx.x * 256 + threadIdx.x;
  if (id < total) dd[id] = f2bf(s[id]);
}

// ---- a[n,r]=x[n].wq[r], b[n,r]=x[n].wk[r]: wave per node ----
__global__ __launch_bounds__(256) void k_ab(const float* __restrict__ x,
    const float* __restrict__ wq, const float* __restrict__ wk,
    float* __restrict__ aT, float* __restrict__ bT, int N, int R){
  __shared__ float lq[8 * D], lk[8 * D];
  for (int i = threadIdx.x; i < R * D; i += 256){ lq[i] = wq[i]; lk[i] = wk[i]; }
  __syncthreads();
  int wv = threadIdx.x >> 6, ln = threadIdx.x & 63;
  int n = blockIdx.x * 4 + wv;
  if (n >= N) return;
  float2 xv = ((const float2*)(x + (size_t)n * D))[ln];
  for (int r = 0; r < R; ++r){
    float pa = xv.x * lq[r * D + 2 * ln] + xv.y * lq[r * D + 2 * ln + 1];
    float pb = xv.x * lk[r * D + 2 * ln] + xv.y * lk[r * D + 2 * ln + 1];
    pa = wred_sum(pa); pb = wred_sum(pb);
    if (ln == 0){ aT[n * R + r] = pa; bT[n * R + r] = pb; }
  }
}

// ---- segment softmax over dst: wave per node ----
__global__ __launch_bounds__(256) void k_alpha(const int* __restrict__ rp,
    const int* __restrict__ pack, const float* __restrict__ aT, const float* __restrict__ bT,
    float* __restrict__ alp, int N, int R){
  int wv = threadIdx.x >> 6, ln = threadIdx.x & 63;
  int n = blockIdx.x * 4 + wv;
  if (n >= N) return;
  int beg = rp[n * R], end = rp[n * R + R];
  if (end <= beg) return;
  float mx = -3.4e38f;
  for (int i = beg + ln; i < end; i += 64){
    int v = pack[i]; int t = v >> 27; int s = v & 0x7ffffff;
    float l = aT[n * R + t] + bT[s * R + t];
    l = l > 0.f ? l : 0.2f * l;
    mx = fmaxf(mx, l);
  }
  mx = wred_max(mx);
  float sm = 0.f;
  for (int i = beg + ln; i < end; i += 64){
    int v = pack[i]; int t = v >> 27; int s = v & 0x7ffffff;
    float l = aT[n * R + t] + bT[s * R + t];
    l = l > 0.f ? l : 0.2f * l;
    float ev = __expf(l - mx);
    alp[i] = ev; sm += ev;
  }
  sm = wred_sum(sm);
  float inv = 1.f / sm;
  for (int i = beg + ln; i < end; i += 64) alp[i] *= inv;
}

// ---- xw[n][r*128+h] = (x[n] @ w[r])[h], bf16, via MFMA.
//      One (tile, r) per block + BIJECTIVE XCD SWIZZLE (m204): all 8 r-blocks
//      of a tile land on the SAME XCD so the x-tile is fetched into that L2
//      once, not 8 times (R7 counters: FETCH 100MB vs 26MB compulsory). ----
__global__ __launch_bounds__(256) void k_xw(const float* __restrict__ x,
    const unsigned short* __restrict__ wbf,  // [R][h][k] bf16
    unsigned short* __restrict__ xw,         // [N][R*128] bf16
    int N, int R, int nwg){
  __shared__ unsigned short ot[64][136];     // 272B rows (17x16B): uint4-aligned
  int wv = threadIdx.x >> 6, ln = threadIdx.x & 63;
  int g = ln >> 4, m16 = ln & 15;
  // bijective chunked swizzle: hw XCD = orig % 8
  int orig = blockIdx.x;
  int q = nwg >> 3, rm = nwg & 7;
  int xcd = orig & 7, idx = orig >> 3;
  int wgid = (xcd < rm ? xcd * (q + 1) : rm * (q + 1) + (xcd - rm) * q) + idx;
  int r    = wgid % 8;                       // R == 8
  int tile = wgid / 8;
  int n0 = tile * 64;
  int nA = n0 + wv * 16 + m16;
  bf16x8 af[4];
#pragma unroll
  for (int kc = 0; kc < 4; ++kc){
    float4 a0 = {0.f,0.f,0.f,0.f}, a1 = {0.f,0.f,0.f,0.f};
    if (nA < N){
      const float* ap = x + (size_t)nA * D + kc * 32 + g * 8;
      a0 = *(const float4*)ap; a1 = *(const float4*)(ap + 4);
    }
    af[kc][0] = (short)f2bf(a0.x); af[kc][1] = (short)f2bf(a0.y);
    af[kc][2] = (short)f2bf(a0.z); af[kc][3] = (short)f2bf(a0.w);
    af[kc][4] = (short)f2bf(a1.x); af[kc][5] = (short)f2bf(a1.y);
    af[kc][6] = (short)f2bf(a1.z); af[kc][7] = (short)f2bf(a1.w);
  }
  int RD128 = R * 128;
  f32x4 acc[8];
#pragma unroll
  for (int i = 0; i < 8; ++i) acc[i] = (f32x4){0.f, 0.f, 0.f, 0.f};
  const unsigned short* wr = wbf + (size_t)r * 16384;
#pragma unroll
  for (int kc = 0; kc < 4; ++kc){
#pragma unroll
    for (int hf = 0; hf < 8; ++hf){
      bf16x8 bfr = *(const bf16x8*)(wr + (hf * 16 + m16) * 128 + kc * 32 + g * 8);
      acc[hf] = __builtin_amdgcn_mfma_f32_16x16x32_bf16(af[kc], bfr, acc[hf], 0, 0, 0);
    }
  }
#pragma unroll
  for (int hf = 0; hf < 8; ++hf){
#pragma unroll
    for (int jj = 0; jj < 4; ++jj){
      ot[wv * 16 + g * 4 + jj][hf * 16 + m16] = f2bf(acc[hf][jj]);
    }
  }
  __syncthreads();
  // cooperative coalesced write: 1024 x uint4 (16 lanes cover 256B of a row)
  for (int i = threadIdx.x; i < 1024; i += 256){
    int row = i >> 4, c16 = i & 15;
    int n = n0 + row;
    if (n < N)
      *(uint4*)(xw + (size_t)n * RD128 + r * 128 + c16 * 8) = *(const uint4*)&ot[row][c16 * 8];
  }
}

// ---- aggregation: one wave per node, 4-wide edge unroll for MLP ----
__global__ __launch_bounds__(256) void k_aggX(const unsigned short* __restrict__ xw,
    const int* __restrict__ rp, const int* __restrict__ pack, const float* __restrict__ alp,
    const float* __restrict__ bias, float* __restrict__ xo, int N, int R){
  int wv = threadIdx.x >> 6, ln = threadIdx.x & 63;
  int n = blockIdx.x * 4 + wv;
  if (n >= N) return;
  int beg = rp[n * R], end = rp[n * R + R];
  int RD128 = R * 128;
  float2 s0 = {0.f, 0.f}, s1 = {0.f, 0.f}, s2 = {0.f, 0.f}, s3 = {0.f, 0.f};
  int i = beg;
  for (; i + 3 < end; i += 4){
    int v0 = pack[i], v1 = pack[i + 1], v2 = pack[i + 2], v3 = pack[i + 3];
    float al0 = alp[i], al1 = alp[i + 1], al2 = alp[i + 2], al3 = alp[i + 3];
    unsigned u0 = *(const unsigned*)(xw + (size_t)(v0 & 0x7ffffff) * RD128 + (v0 >> 27) * 128 + 2 * ln);
    unsigned u1 = *(const unsigned*)(xw + (size_t)(v1 & 0x7ffffff) * RD128 + (v1 >> 27) * 128 + 2 * ln);
    unsigned u2 = *(const unsigned*)(xw + (size_t)(v2 & 0x7ffffff) * RD128 + (v2 >> 27) * 128 + 2 * ln);
    unsigned u3 = *(const unsigned*)(xw + (size_t)(v3 & 0x7ffffff) * RD128 + (v3 >> 27) * 128 + 2 * ln);
    s0.x += al0 * __uint_as_float(u0 << 16);
    s0.y += al0 * __uint_as_float(u0 & 0xffff0000u);
    s1.x += al1 * __uint_as_float(u1 << 16);
    s1.y += al1 * __uint_as_float(u1 & 0xffff0000u);
    s2.x += al2 * __uint_as_float(u2 << 16);
    s2.y += al2 * __uint_as_float(u2 & 0xffff0000u);
    s3.x += al3 * __uint_as_float(u3 << 16);
    s3.y += al3 * __uint_as_float(u3 & 0xffff0000u);
  }
  for (; i < end; ++i){
    int v0 = pack[i];
    float al0 = alp[i];
    unsigned u0 = *(const unsigned*)(xw + (size_t)(v0 & 0x7ffffff) * RD128 + (v0 >> 27) * 128 + 2 * ln);
    s0.x += al0 * __uint_as_float(u0 << 16);
    s0.y += al0 * __uint_as_float(u0 & 0xffff0000u);
  }
  float2 o;
  o.x = fmaxf(s0.x + s1.x + s2.x + s3.x + bias[2 * ln], 0.f);
  o.y = fmaxf(s0.y + s1.y + s2.y + s3.y + bias[2 * ln + 1], 0.f);
  ((float2*)(xo + (size_t)n * D))[ln] = o;
}

// ---- fallback: fused aggregate (S-tile in LDS) + MFMA GEMM + bias + relu ----
__global__ __launch_bounds__(256) void k_agg(const float* __restrict__ x_in,
    const unsigned short* __restrict__ wbf, const float* __restrict__ bias,
    const int* __restrict__ rp, const int* __restrict__ pack,
    const float* __restrict__ alp, float* __restrict__ x_out, int N, int R){
  __shared__ float st[64][132];
  __shared__ unsigned short wt[128][136];
  int wv = threadIdx.x >> 6, ln = threadIdx.x & 63;
  int g = ln >> 4, m16 = ln & 15;
  int n0 = blockIdx.x * 64;
  f32x4 acc[8];
#pragma unroll
  for (int i = 0; i < 8; ++i) acc[i] = (f32x4){0.f, 0.f, 0.f, 0.f};

  for (int r = 0; r < R; ++r){
    __syncthreads();
    {
      const uint4* src = (const uint4*)(wbf + (size_t)r * 16384);
      for (int i = threadIdx.x; i < 2048; i += 256){
        int h = i >> 4, dblk = i & 15;
        *(uint4*)&wt[h][dblk * 8] = src[i];
      }
    }
    for (int j = 0; j < 16; ++j){
      int n = n0 + wv * 16 + j;
      float2 s2 = {0.f, 0.f};
      if (n < N){
        int beg = rp[n * R + r], end = rp[n * R + r + 1];
        for (int i = beg; i < end; ++i){
          int s = pack[i] & 0x7ffffff;
          float al = alp[i];
          float2 xv = ((const float2*)(x_in + (size_t)s * D))[ln];
          s2.x += al * xv.x; s2.y += al * xv.y;
        }
      }
      *(float2*)&st[wv * 16 + j][2 * ln] = s2;
    }
    __syncthreads();
#pragma unroll
    for (int kc = 0; kc < 4; ++kc){
      const float* ap = &st[wv * 16 + m16][kc * 32 + g * 8];
      float4 a0 = *(const float4*)ap;
      float4 a1 = *(const float4*)(ap + 4);
      bf16x8 af;
      af[0] = (short)f2bf(a0.x); af[1] = (short)f2bf(a0.y);
      af[2] = (short)f2bf(a0.z); af[3] = (short)f2bf(a0.w);
      af[4] = (short)f2bf(a1.x); af[5] = (short)f2bf(a1.y);
      af[6] = (short)f2bf(a1.z); af[7] = (short)f2bf(a1.w);
#pragma unroll
      for (int hf = 0; hf < 8; ++hf){
        bf16x8 bfr = *(const bf16x8*)&wt[hf * 16 + m16][kc * 32 + g * 8];
        acc[hf] = __builtin_amdgcn_mfma_f32_16x16x32_bf16(af, bfr, acc[hf], 0, 0, 0);
      }
    }
  }
#pragma unroll
  for (int hf = 0; hf < 8; ++hf){
    int h = hf * 16 + m16;
    float bv = bias[h];
#pragma unroll
    for (int jj = 0; jj < 4; ++jj){
      int n = n0 + wv * 16 + g * 4 + jj;
      if (n < N){
        float v = acc[hf][jj] + bv;
        x_out[(size_t)n * D + h] = fmaxf(v, 0.f);
      }
    }
  }
}

// ---- final linear + per-graph segment sum: LDS per-block reduce over sorted
// batch runs, then ONE atomicAdd per (graph,h) run present in the tile ----
__global__ __launch_bounds__(256) void k_final(const float* __restrict__ x,
    const unsigned short* __restrict__ lwbf, const float* __restrict__ lb,
    const int* __restrict__ batch, float* __restrict__ out, int N){
  __shared__ unsigned short wt[128][136]; // lin_w [h][k] bf16
  __shared__ float st[64][129];           // per-node output rows
  __shared__ int bsh[64];
  {
    const uint4* src = (const uint4*)lwbf;
    for (int i = threadIdx.x; i < 2048; i += 256){
      int h = i >> 4, kblk = i & 15;
      *(uint4*)&wt[h][kblk * 8] = src[i];
    }
  }
  __syncthreads();
  int wv = threadIdx.x >> 6, ln = threadIdx.x & 63;
  int g = ln >> 4, m16 = ln & 15;
  int n0 = blockIdx.x * 64;
  f32x4 acc[8];
#pragma unroll
  for (int i = 0; i < 8; ++i) acc[i] = (f32x4){0.f, 0.f, 0.f, 0.f};
#pragma unroll
  for (int kc = 0; kc < 4; ++kc){
    int nA = n0 + wv * 16 + m16;
    float4 a0 = {0.f,0.f,0.f,0.f}, a1 = {0.f,0.f,0.f,0.f};
    if (nA < N){
      const float* ap = x + (size_t)nA * D + kc * 32 + g * 8;
      a0 = *(const float4*)ap; a1 = *(const float4*)(ap + 4);
    }
    bf16x8 af;
    af[0] = (short)f2bf(a0.x); af[1] = (short)f2bf(a0.y);
    af[2] = (short)f2bf(a0.z); af[3] = (short)f2bf(a0.w);
    af[4] = (short)f2bf(a1.x); af[5] = (short)f2bf(a1.y);
    af[6] = (short)f2bf(a1.z); af[7] = (short)f2bf(a1.w);
#pragma unroll
    for (int hf = 0; hf < 8; ++hf){
      bf16x8 bfr = *(const bf16x8*)&wt[hf * 16 + m16][kc * 32 + g * 8];
      acc[hf] = __builtin_amdgcn_mfma_f32_16x16x32_bf16(af, bfr, acc[hf], 0, 0, 0);
    }
  }
  // rows -> LDS (per-node bias added here; invalid rows zeroed)
#pragma unroll
  for (int hf = 0; hf < 8; ++hf){
    int h = hf * 16 + m16;
    float bv = lb[h];
#pragma unroll
    for (int jj = 0; jj < 4; ++jj){
      int row = wv * 16 + g * 4 + jj;
      int n = n0 + row;
      st[row][h] = (n < N) ? (acc[hf][jj] + bv) : 0.f;
    }
  }
  if (threadIdx.x < 64){
    int n = n0 + threadIdx.x;
    bsh[threadIdx.x] = (n < N) ? batch[n] : -1;
  }
  __syncthreads();
  // scan sorted rows, one atomic per (graph,h) run
  if (threadIdx.x < 128){
    int h = threadIdx.x;
    int lastValid = (N - n0 < 64) ? (N - n0 - 1) : 63;
    int cg = bsh[0];
    float sum = 0.f;
    for (int row = 0; row <= lastValid; ++row){
      int bg = bsh[row];
      if (bg != cg){
        atomicAdd(&out[(size_t)cg * D + h], sum);
        sum = 0.f; cg = bg;
      }
      sum += st[row][h];
    }
    atomicAdd(&out[(size_t)cg * D + h], sum);
  }
}

extern "C" void kernel_launch(void* const* d_in, const int* in_sizes, int n_in,
                              void* d_out, int out_size, void* d_ws, size_t ws_size,
                              hipStream_t stream){
  const int*   xpad  = (const int*)d_in[0];
  const int*   eidx  = (const int*)d_in[1];
  const int*   etyp  = (const int*)d_in[2];
  const int*   batch = (const int*)d_in[3];
  const float* emb   = (const float*)d_in[4];
  const float* w1    = (const float*)d_in[5];
  const float* q1    = (const float*)d_in[6];
  const float* k1    = (const float*)d_in[7];
  const float* b1    = (const float*)d_in[8];
  const float* w2    = (const float*)d_in[9];
  const float* q2    = (const float*)d_in[10];
  const float* k2    = (const float*)d_in[11];
  const float* b2    = (const float*)d_in[12];
  const float* lw    = (const float*)d_in[13];
  const float* lb    = (const float*)d_in[14];

  int N = in_sizes[3];
  int M = in_sizes[0] / N;
  int E = in_sizes[2];
  int R = in_sizes[5] / (128 * 128);
  int NB = N * R;
  const int* esrc = eidx;
  const int* edst = eidx + E;

  char* p = (char*)d_ws;
  auto carve = [&](size_t b) -> void* {
    void* q = (void*)p; p += (b + 255) & ~(size_t)255; return q;
  };
  float* x_a  = (float*)carve((size_t)N * D * 4);
  float* x_b  = (float*)carve((size_t)N * D * 4);
  float* wq1  = (float*)carve((size_t)R * D * 4);
  float* wk1  = (float*)carve((size_t)R * D * 4);
  float* wq2  = (float*)carve((size_t)R * D * 4);
  float* wk2  = (float*)carve((size_t)R * D * 4);
  float* aT   = (float*)carve((size_t)N * R * 4);
  float* bT   = (float*)carve((size_t)N * R * 4);
  int*   rp   = (int*)carve((size_t)(NB + 1) * 4);
  int*   cur  = (int*)carve((size_t)NB * 4);
  int*   pack = (int*)carve((size_t)E * 4);
  float* alp  = (float*)carve((size_t)E * 4);
  unsigned short* wbf1 = (unsigned short*)carve((size_t)R * 128 * 128 * 2);
  unsigned short* wbf2 = (unsigned short*)carve((size_t)R * 128 * 128 * 2);
  unsigned short* lwbf = (unsigned short*)carve((size_t)128 * 128 * 2);
  int* bsum = (int*)carve((size_t)4096 * 4);
  int* boff = (int*)carve((size_t)4096 * 4);
  if ((size_t)(p - (char*)d_ws) > ws_size) return;  // base ws too small: fail visibly
  unsigned short* xw = (unsigned short*)carve((size_t)N * R * 128 * 2);
  bool use_xw = ((size_t)(p - (char*)d_ws) <= ws_size);

  hipMemsetAsync(cur, 0, (size_t)NB * 4, stream);
  hipMemsetAsync(d_out, 0, (size_t)out_size * 4, stream);

  int eg = (E + 255) / 256;
  int nblk = (NB + 1023) / 1024;
  k_count   <<<eg, 256, 0, stream>>>(edst, etyp, cur, E, R);
  k_scan_blk<<<nblk, 256, 0, stream>>>(cur, bsum, NB);
  k_scan_top<<<1, 1024, 0, stream>>>(bsum, boff, rp, nblk, NB);
  k_scan_fin<<<nblk, 256, 0, stream>>>(cur, boff, rp, NB);
  k_scatter <<<eg, 256, 0, stream>>>(esrc, edst, etyp, cur, pack, E, R);

  k_wqk<<<(R * D + 255) / 256, 256, 0, stream>>>(w1, q1, k1, wq1, wk1, R * D);
  k_wqk<<<(R * D + 255) / 256, 256, 0, stream>>>(w2, q2, k2, wq2, wk2, R * D);
  int wtot = R * 128 * 128;
  k_wtr<<<(wtot + 255) / 256, 256, 0, stream>>>(w1, wbf1, wtot);
  k_wtr<<<(wtot + 255) / 256, 256, 0, stream>>>(w2, wbf2, wtot);
  k_cvt<<<(128 * 128 + 255) / 256, 256, 0, stream>>>(lw, lwbf, 128 * 128);

  int ng4 = (N + 3) / 4;
  int ntile = (N + 63) / 64;
  int nwg = ntile * R;
  k_pool<<<ng4, 256, 0, stream>>>(xpad, emb, x_a, N, M);

  // layer 1
  k_ab   <<<ng4, 256, 0, stream>>>(x_a, wq1, wk1, aT, bT, N, R);
  k_alpha<<<ng4, 256, 0, stream>>>(rp, pack, aT, bT, alp, N, R);
  if (use_xw){
    k_xw  <<<nwg, 256, 0, stream>>>(x_a, wbf1, xw, N, R, nwg);
    k_aggX<<<ng4, 256, 0, stream>>>(xw, rp, pack, alp, b1, x_b, N, R);
  } else {
    k_agg <<<ntile, 256, 0, stream>>>(x_a, wbf1, b1, rp, pack, alp, x_b, N, R);
  }

  // layer 2
  k_ab   <<<ng4, 256, 0, stream>>>(x_b, wq2, wk2, aT, bT, N, R);
  k_alpha<<<ng4, 256, 0, stream>>>(rp, pack, aT, bT, alp, N, R);
  if (use_xw){
    k_xw  <<<nwg, 256, 0, stream>>>(x_b, wbf2, xw, N, R, nwg);
    k_aggX<<<ng4, 256, 0, stream>>>(xw, rp, pack, alp, b2, x_a, N, R);
  } else {
    k_agg <<<ntile, 256, 0, stream>>>(x_b, wbf2, b2, rp, pack, alp, x_a, N, R);
  }

  // final linear + graph segment-sum
  k_final<<<ntile, 256, 0, stream>>>(x_a, lwbf, lb, batch, (float*)d_out, N);
}

// Round 9
// 635.425 us; speedup vs baseline: 3.5196x; 1.0052x over previous
//
#include <hip/hip_runtime.h>
#include <hip/hip_bf16.h>
#include <math.h>

#define D 128

typedef __attribute__((ext_vector_type(4))) float f32x4;
typedef __attribute__((ext_vector_type(8))) short bf16x8;

__device__ inline unsigned short f2bf(float f){
  unsigned u = __float_as_uint(f);
  u += 0x7fffu + ((u >> 16) & 1u);
  return (unsigned short)(u >> 16);
}
__device__ inline float wred_sum(float v){
#pragma unroll
  for (int m = 1; m < 64; m <<= 1) v += __shfl_xor(v, m, 64);
  return v;
}
__device__ inline float wred_max(float v){
#pragma unroll
  for (int m = 1; m < 64; m <<= 1) v = fmaxf(v, __shfl_xor(v, m, 64));
  return v;
}

// ---- embedding mean-pool: wave per node; padding is suffix-only ----
__global__ __launch_bounds__(256) void k_pool(const int* __restrict__ xpad,
    const float* __restrict__ emb, float* __restrict__ xo, int N, int M){
  int wv = threadIdx.x >> 6, ln = threadIdx.x & 63;
  int n = blockIdx.x * 4 + wv;
  if (n >= N) return;
  int cnt = 0;
  while (cnt < M && xpad[n * M + cnt] >= 0) ++cnt;
  float2 acc = {0.f, 0.f};
  int m = 0;
  for (; m + 1 < cnt; m += 2){
    int i0 = xpad[n * M + m], i1 = xpad[n * M + m + 1];
    float2 v0 = ((const float2*)(emb + (size_t)i0 * D))[ln];
    float2 v1 = ((const float2*)(emb + (size_t)i1 * D))[ln];
    acc.x += v0.x + v1.x; acc.y += v0.y + v1.y;
  }
  if (m < cnt){
    int i0 = xpad[n * M + m];
    float2 v0 = ((const float2*)(emb + (size_t)i0 * D))[ln];
    acc.x += v0.x; acc.y += v0.y;
  }
  float inv = 1.f / (float)cnt;
  float2 o; o.x = acc.x * inv; o.y = acc.y * inv;
  ((float2*)(xo + (size_t)n * D))[ln] = o;
}

// ---- CSR build over buckets (dst*R + et) ----
__global__ void k_count(const int* __restrict__ dst, const int* __restrict__ et,
                        int* __restrict__ cnt, int E, int R){
  int e = blockIdx.x * 256 + threadIdx.x;
  if (e < E) atomicAdd(&cnt[dst[e] * R + et[e]], 1);
}

// ---- hierarchical exclusive scan over nb buckets (1024 elems / block) ----
__global__ __launch_bounds__(256) void k_scan_blk(const int* __restrict__ cc,
    int* __restrict__ bsum, int nb){
  __shared__ int sh[256];
  int base = blockIdx.x * 1024 + threadIdx.x * 4;
  int s = 0;
#pragma unroll
  for (int j = 0; j < 4; ++j){
    int i = base + j;
    if (i < nb) s += cc[i];
  }
  sh[threadIdx.x] = s; __syncthreads();
  for (int off = 128; off > 0; off >>= 1){
    if (threadIdx.x < off) sh[threadIdx.x] += sh[threadIdx.x + off];
    __syncthreads();
  }
  if (threadIdx.x == 0) bsum[blockIdx.x] = sh[0];
}

__global__ __launch_bounds__(1024) void k_scan_top(const int* __restrict__ bsum,
    int* __restrict__ boff, int* __restrict__ rp, int nblk, int nb){
  __shared__ int sh[1024];
  int t = threadIdx.x;
  int v = (t < nblk) ? bsum[t] : 0;
  sh[t] = v; __syncthreads();
  for (int off = 1; off < 1024; off <<= 1){
    int a = sh[t];
    int b = (t >= off) ? sh[t - off] : 0;
    __syncthreads();
    sh[t] = a + b;
    __syncthreads();
  }
  if (t < nblk) boff[t] = sh[t] - v;       // exclusive
  if (t == 1023) rp[nb] = sh[1023];        // total
}

__global__ __launch_bounds__(256) void k_scan_fin(int* __restrict__ cc,
    const int* __restrict__ boff, int* __restrict__ rp, int nb){
  __shared__ int sh[256];
  int t = threadIdx.x;
  int base = blockIdx.x * 1024 + t * 4;
  int c[4]; int local = 0;
#pragma unroll
  for (int j = 0; j < 4; ++j){
    int i = base + j;
    c[j] = (i < nb) ? cc[i] : 0;
    local += c[j];
  }
  sh[t] = local; __syncthreads();
  for (int off = 1; off < 256; off <<= 1){
    int a = sh[t];
    int b = (t >= off) ? sh[t - off] : 0;
    __syncthreads();
    sh[t] = a + b;
    __syncthreads();
  }
  int run = sh[t] - local + boff[blockIdx.x];
#pragma unroll
  for (int j = 0; j < 4; ++j){
    int i = base + j;
    if (i < nb){ rp[i] = run; cc[i] = run; run += c[j]; }
  }
}

__global__ void k_scatter(const int* __restrict__ src, const int* __restrict__ dst,
    const int* __restrict__ et, int* __restrict__ cur, int* __restrict__ pack, int E, int R){
  int e = blockIdx.x * 256 + threadIdx.x;
  if (e < E){
    int t = et[e];
    int p = atomicAdd(&cur[dst[e] * R + t], 1);
    pack[p] = (t << 27) | src[e];
  }
}

// ---- wq[r][d] = sum_h w[r][d][h]*q[h]; wk likewise ----
__global__ void k_wqk(const float* __restrict__ w, const float* __restrict__ q,
    const float* __restrict__ kk, float* __restrict__ wq, float* __restrict__ wk, int RD){
  int id = blockIdx.x * 256 + threadIdx.x;
  if (id >= RD) return;
  const float* wr = w + (size_t)id * D;
  float sq = 0.f, sk = 0.f;
  for (int h = 0; h < D; ++h){ float v = wr[h]; sq += v * q[h]; sk += v * kk[h]; }
  wq[id] = sq; wk[id] = sk;
}

// ---- w[r][d][h] fp32 -> wbf[r][h][d] bf16 (transposed) ----
__global__ void k_wtr(const float* __restrict__ w, unsigned short* __restrict__ wbf, int total){
  int id = blockIdx.x * 256 + threadIdx.x;
  if (id >= total) return;
  int d = id & 127, h = (id >> 7) & 127, r = id >> 14;
  wbf[id] = f2bf(w[(size_t)r * 16384 + d * 128 + h]);
}

// ---- plain fp32 -> bf16 convert (no transpose) ----
__global__ void k_cvt(const float* __restrict__ s, unsigned short* __restrict__ dd, int total){
  int id = blockIdx.x * 256 + threadIdx.x;
  if (id < total) dd[id] = f2bf(s[id]);
}

// ---- a[n,r]=x[n].wq[r], b[n,r]=x[n].wk[r]: wave per node ----
__global__ __launch_bounds__(256) void k_ab(const float* __restrict__ x,
    const float* __restrict__ wq, const float* __restrict__ wk,
    float* __restrict__ aT, float* __restrict__ bT, int N, int R){
  __shared__ float lq[8 * D], lk[8 * D];
  for (int i = threadIdx.x; i < R * D; i += 256){ lq[i] = wq[i]; lk[i] = wk[i]; }
  __syncthreads();
  int wv = threadIdx.x >> 6, ln = threadIdx.x & 63;
  int n = blockIdx.x * 4 + wv;
  if (n >= N) return;
  float2 xv = ((const float2*)(x + (size_t)n * D))[ln];
  for (int r = 0; r < R; ++r){
    float pa = xv.x * lq[r * D + 2 * ln] + xv.y * lq[r * D + 2 * ln + 1];
    float pb = xv.x * lk[r * D + 2 * ln] + xv.y * lk[r * D + 2 * ln + 1];
    pa = wred_sum(pa); pb = wred_sum(pb);
    if (ln == 0){ aT[n * R + r] = pa; bT[n * R + r] = pb; }
  }
}

// ---- segment softmax over dst: wave per node ----
__global__ __launch_bounds__(256) void k_alpha(const int* __restrict__ rp,
    const int* __restrict__ pack, const float* __restrict__ aT, const float* __restrict__ bT,
    float* __restrict__ alp, int N, int R){
  int wv = threadIdx.x >> 6, ln = threadIdx.x & 63;
  int n = blockIdx.x * 4 + wv;
  if (n >= N) return;
  int beg = rp[n * R], end = rp[n * R + R];
  if (end <= beg) return;
  float mx = -3.4e38f;
  for (int i = beg + ln; i < end; i += 64){
    int v = pack[i]; int t = v >> 27; int s = v & 0x7ffffff;
    float l = aT[n * R + t] + bT[s * R + t];
    l = l > 0.f ? l : 0.2f * l;
    mx = fmaxf(mx, l);
  }
  mx = wred_max(mx);
  float sm = 0.f;
  for (int i = beg + ln; i < end; i += 64){
    int v = pack[i]; int t = v >> 27; int s = v & 0x7ffffff;
    float l = aT[n * R + t] + bT[s * R + t];
    l = l > 0.f ? l : 0.2f * l;
    float ev = __expf(l - mx);
    alp[i] = ev; sm += ev;
  }
  sm = wred_sum(sm);
  float inv = 1.f / sm;
  for (int i = beg + ln; i < end; i += 64) alp[i] *= inv;
}

// ---- xw[n][r*128+h] = (x[n] @ w[r])[h], bf16, via MFMA.
//      TWO relations per block (amortize the per-block latency chain:
//      x-load + barrier + store serve 64 MFMAs instead of 32) +
//      bijective XCD swizzle so the 4 blocks sharing an x-tile land on
//      one XCD's L2 (R8: FETCH 13.7MB, x fully L2-resident). ----
__global__ __launch_bounds__(256) void k_xw(const float* __restrict__ x,
    const unsigned short* __restrict__ wbf,  // [R][h][k] bf16
    unsigned short* __restrict__ xw,         // [N][R*128] bf16
    int N, int R, int nwg){
  __shared__ unsigned short ot[2][64][136];  // 272B rows (17x16B): uint4-aligned
  int wv = threadIdx.x >> 6, ln = threadIdx.x & 63;
  int g = ln >> 4, m16 = ln & 15;
  // bijective chunked swizzle: hw XCD = orig % 8
  int orig = blockIdx.x;
  int q = nwg >> 3, rm = nwg & 7;
  int xcd = orig & 7, idx = orig >> 3;
  int wgid = (xcd < rm ? xcd * (q + 1) : rm * (q + 1) + (xcd - rm) * q) + idx;
  int rq   = wgid & 3;                       // relation pair: r = rq*2, rq*2+1
  int tile = wgid >> 2;
  int n0 = tile * 64;
  int nA = n0 + wv * 16 + m16;
  bf16x8 af[4];
#pragma unroll
  for (int kc = 0; kc < 4; ++kc){
    float4 a0 = {0.f,0.f,0.f,0.f}, a1 = {0.f,0.f,0.f,0.f};
    if (nA < N){
      const float* ap = x + (size_t)nA * D + kc * 32 + g * 8;
      a0 = *(const float4*)ap; a1 = *(const float4*)(ap + 4);
    }
    af[kc][0] = (short)f2bf(a0.x); af[kc][1] = (short)f2bf(a0.y);
    af[kc][2] = (short)f2bf(a0.z); af[kc][3] = (short)f2bf(a0.w);
    af[kc][4] = (short)f2bf(a1.x); af[kc][5] = (short)f2bf(a1.y);
    af[kc][6] = (short)f2bf(a1.z); af[kc][7] = (short)f2bf(a1.w);
  }
  int RD128 = R * 128;
  f32x4 acc0[8], acc1[8];
#pragma unroll
  for (int i = 0; i < 8; ++i){
    acc0[i] = (f32x4){0.f, 0.f, 0.f, 0.f};
    acc1[i] = (f32x4){0.f, 0.f, 0.f, 0.f};
  }
  const unsigned short* wr0 = wbf + (size_t)(rq * 2)     * 16384;
  const unsigned short* wr1 = wbf + (size_t)(rq * 2 + 1) * 16384;
#pragma unroll
  for (int kc = 0; kc < 4; ++kc){
#pragma unroll
    for (int hf = 0; hf < 8; ++hf){
      bf16x8 b0 = *(const bf16x8*)(wr0 + (hf * 16 + m16) * 128 + kc * 32 + g * 8);
      bf16x8 b1 = *(const bf16x8*)(wr1 + (hf * 16 + m16) * 128 + kc * 32 + g * 8);
      acc0[hf] = __builtin_amdgcn_mfma_f32_16x16x32_bf16(af[kc], b0, acc0[hf], 0, 0, 0);
      acc1[hf] = __builtin_amdgcn_mfma_f32_16x16x32_bf16(af[kc], b1, acc1[hf], 0, 0, 0);
    }
  }
#pragma unroll
  for (int hf = 0; hf < 8; ++hf){
#pragma unroll
    for (int jj = 0; jj < 4; ++jj){
      ot[0][wv * 16 + g * 4 + jj][hf * 16 + m16] = f2bf(acc0[hf][jj]);
      ot[1][wv * 16 + g * 4 + jj][hf * 16 + m16] = f2bf(acc1[hf][jj]);
    }
  }
  __syncthreads();
  // cooperative coalesced write: 2048 x uint4 (16 lanes cover 256B of a row)
  for (int i = threadIdx.x; i < 2048; i += 256){
    int buf = i >> 10, rem = i & 1023;
    int row = rem >> 4, c16 = rem & 15;
    int n = n0 + row;
    if (n < N)
      *(uint4*)(xw + (size_t)n * RD128 + (rq * 2 + buf) * 128 + c16 * 8)
          = *(const uint4*)&ot[buf][row][c16 * 8];
  }
}

// ---- aggregation: one wave per node, 4-wide edge unroll for MLP ----
__global__ __launch_bounds__(256) void k_aggX(const unsigned short* __restrict__ xw,
    const int* __restrict__ rp, const int* __restrict__ pack, const float* __restrict__ alp,
    const float* __restrict__ bias, float* __restrict__ xo, int N, int R){
  int wv = threadIdx.x >> 6, ln = threadIdx.x & 63;
  int n = blockIdx.x * 4 + wv;
  if (n >= N) return;
  int beg = rp[n * R], end = rp[n * R + R];
  int RD128 = R * 128;
  float2 s0 = {0.f, 0.f}, s1 = {0.f, 0.f}, s2 = {0.f, 0.f}, s3 = {0.f, 0.f};
  int i = beg;
  for (; i + 3 < end; i += 4){
    int v0 = pack[i], v1 = pack[i + 1], v2 = pack[i + 2], v3 = pack[i + 3];
    float al0 = alp[i], al1 = alp[i + 1], al2 = alp[i + 2], al3 = alp[i + 3];
    unsigned u0 = *(const unsigned*)(xw + (size_t)(v0 & 0x7ffffff) * RD128 + (v0 >> 27) * 128 + 2 * ln);
    unsigned u1 = *(const unsigned*)(xw + (size_t)(v1 & 0x7ffffff) * RD128 + (v1 >> 27) * 128 + 2 * ln);
    unsigned u2 = *(const unsigned*)(xw + (size_t)(v2 & 0x7ffffff) * RD128 + (v2 >> 27) * 128 + 2 * ln);
    unsigned u3 = *(const unsigned*)(xw + (size_t)(v3 & 0x7ffffff) * RD128 + (v3 >> 27) * 128 + 2 * ln);
    s0.x += al0 * __uint_as_float(u0 << 16);
    s0.y += al0 * __uint_as_float(u0 & 0xffff0000u);
    s1.x += al1 * __uint_as_float(u1 << 16);
    s1.y += al1 * __uint_as_float(u1 & 0xffff0000u);
    s2.x += al2 * __uint_as_float(u2 << 16);
    s2.y += al2 * __uint_as_float(u2 & 0xffff0000u);
    s3.x += al3 * __uint_as_float(u3 << 16);
    s3.y += al3 * __uint_as_float(u3 & 0xffff0000u);
  }
  for (; i < end; ++i){
    int v0 = pack[i];
    float al0 = alp[i];
    unsigned u0 = *(const unsigned*)(xw + (size_t)(v0 & 0x7ffffff) * RD128 + (v0 >> 27) * 128 + 2 * ln);
    s0.x += al0 * __uint_as_float(u0 << 16);
    s0.y += al0 * __uint_as_float(u0 & 0xffff0000u);
  }
  float2 o;
  o.x = fmaxf(s0.x + s1.x + s2.x + s3.x + bias[2 * ln], 0.f);
  o.y = fmaxf(s0.y + s1.y + s2.y + s3.y + bias[2 * ln + 1], 0.f);
  ((float2*)(xo + (size_t)n * D))[ln] = o;
}

// ---- fallback: fused aggregate (S-tile in LDS) + MFMA GEMM + bias + relu ----
__global__ __launch_bounds__(256) void k_agg(const float* __restrict__ x_in,
    const unsigned short* __restrict__ wbf, const float* __restrict__ bias,
    const int* __restrict__ rp, const int* __restrict__ pack,
    const float* __restrict__ alp, float* __restrict__ x_out, int N, int R){
  __shared__ float st[64][132];
  __shared__ unsigned short wt[128][136];
  int wv = threadIdx.x >> 6, ln = threadIdx.x & 63;
  int g = ln >> 4, m16 = ln & 15;
  int n0 = blockIdx.x * 64;
  f32x4 acc[8];
#pragma unroll
  for (int i = 0; i < 8; ++i) acc[i] = (f32x4){0.f, 0.f, 0.f, 0.f};

  for (int r = 0; r < R; ++r){
    __syncthreads();
    {
      const uint4* src = (const uint4*)(wbf + (size_t)r * 16384);
      for (int i = threadIdx.x; i < 2048; i += 256){
        int h = i >> 4, dblk = i & 15;
        *(uint4*)&wt[h][dblk * 8] = src[i];
      }
    }
    for (int j = 0; j < 16; ++j){
      int n = n0 + wv * 16 + j;
      float2 s2 = {0.f, 0.f};
      if (n < N){
        int beg = rp[n * R + r], end = rp[n * R + r + 1];
        for (int i = beg; i < end; ++i){
          int s = pack[i] & 0x7ffffff;
          float al = alp[i];
          float2 xv = ((const float2*)(x_in + (size_t)s * D))[ln];
          s2.x += al * xv.x; s2.y += al * xv.y;
        }
      }
      *(float2*)&st[wv * 16 + j][2 * ln] = s2;
    }
    __syncthreads();
#pragma unroll
    for (int kc = 0; kc < 4; ++kc){
      const float* ap = &st[wv * 16 + m16][kc * 32 + g * 8];
      float4 a0 = *(const float4*)ap;
      float4 a1 = *(const float4*)(ap + 4);
      bf16x8 af;
      af[0] = (short)f2bf(a0.x); af[1] = (short)f2bf(a0.y);
      af[2] = (short)f2bf(a0.z); af[3] = (short)f2bf(a0.w);
      af[4] = (short)f2bf(a1.x); af[5] = (short)f2bf(a1.y);
      af[6] = (short)f2bf(a1.z); af[7] = (short)f2bf(a1.w);
#pragma unroll
      for (int hf = 0; hf < 8; ++hf){
        bf16x8 bfr = *(const bf16x8*)&wt[hf * 16 + m16][kc * 32 + g * 8];
        acc[hf] = __builtin_amdgcn_mfma_f32_16x16x32_bf16(af, bfr, acc[hf], 0, 0, 0);
      }
    }
  }
#pragma unroll
  for (int hf = 0; hf < 8; ++hf){
    int h = hf * 16 + m16;
    float bv = bias[h];
#pragma unroll
    for (int jj = 0; jj < 4; ++jj){
      int n = n0 + wv * 16 + g * 4 + jj;
      if (n < N){
        float v = acc[hf][jj] + bv;
        x_out[(size_t)n * D + h] = fmaxf(v, 0.f);
      }
    }
  }
}

// ---- final linear + per-graph segment sum: LDS per-block reduce over sorted
// batch runs, then ONE atomicAdd per (graph,h) run present in the tile ----
__global__ __launch_bounds__(256) void k_final(const float* __restrict__ x,
    const unsigned short* __restrict__ lwbf, const float* __restrict__ lb,
    const int* __restrict__ batch, float* __restrict__ out, int N){
  __shared__ unsigned short wt[128][136]; // lin_w [h][k] bf16
  __shared__ float st[64][129];           // per-node output rows
  __shared__ int bsh[64];
  {
    const uint4* src = (const uint4*)lwbf;
    for (int i = threadIdx.x; i < 2048; i += 256){
      int h = i >> 4, kblk = i & 15;
      *(uint4*)&wt[h][kblk * 8] = src[i];
    }
  }
  __syncthreads();
  int wv = threadIdx.x >> 6, ln = threadIdx.x & 63;
  int g = ln >> 4, m16 = ln & 15;
  int n0 = blockIdx.x * 64;
  f32x4 acc[8];
#pragma unroll
  for (int i = 0; i < 8; ++i) acc[i] = (f32x4){0.f, 0.f, 0.f, 0.f};
#pragma unroll
  for (int kc = 0; kc < 4; ++kc){
    int nA = n0 + wv * 16 + m16;
    float4 a0 = {0.f,0.f,0.f,0.f}, a1 = {0.f,0.f,0.f,0.f};
    if (nA < N){
      const float* ap = x + (size_t)nA * D + kc * 32 + g * 8;
      a0 = *(const float4*)ap; a1 = *(const float4*)(ap + 4);
    }
    bf16x8 af;
    af[0] = (short)f2bf(a0.x); af[1] = (short)f2bf(a0.y);
    af[2] = (short)f2bf(a0.z); af[3] = (short)f2bf(a0.w);
    af[4] = (short)f2bf(a1.x); af[5] = (short)f2bf(a1.y);
    af[6] = (short)f2bf(a1.z); af[7] = (short)f2bf(a1.w);
#pragma unroll
    for (int hf = 0; hf < 8; ++hf){
      bf16x8 bfr = *(const bf16x8*)&wt[hf * 16 + m16][kc * 32 + g * 8];
      acc[hf] = __builtin_amdgcn_mfma_f32_16x16x32_bf16(af, bfr, acc[hf], 0, 0, 0);
    }
  }
  // rows -> LDS (per-node bias added here; invalid rows zeroed)
#pragma unroll
  for (int hf = 0; hf < 8; ++hf){
    int h = hf * 16 + m16;
    float bv = lb[h];
#pragma unroll
    for (int jj = 0; jj < 4; ++jj){
      int row = wv * 16 + g * 4 + jj;
      int n = n0 + row;
      st[row][h] = (n < N) ? (acc[hf][jj] + bv) : 0.f;
    }
  }
  if (threadIdx.x < 64){
    int n = n0 + threadIdx.x;
    bsh[threadIdx.x] = (n < N) ? batch[n] : -1;
  }
  __syncthreads();
  // scan sorted rows, one atomic per (graph,h) run
  if (threadIdx.x < 128){
    int h = threadIdx.x;
    int lastValid = (N - n0 < 64) ? (N - n0 - 1) : 63;
    int cg = bsh[0];
    float sum = 0.f;
    for (int row = 0; row <= lastValid; ++row){
      int bg = bsh[row];
      if (bg != cg){
        atomicAdd(&out[(size_t)cg * D + h], sum);
        sum = 0.f; cg = bg;
      }
      sum += st[row][h];
    }
    atomicAdd(&out[(size_t)cg * D + h], sum);
  }
}

extern "C" void kernel_launch(void* const* d_in, const int* in_sizes, int n_in,
                              void* d_out, int out_size, void* d_ws, size_t ws_size,
                              hipStream_t stream){
  const int*   xpad  = (const int*)d_in[0];
  const int*   eidx  = (const int*)d_in[1];
  const int*   etyp  = (const int*)d_in[2];
  const int*   batch = (const int*)d_in[3];
  const float* emb   = (const float*)d_in[4];
  const float* w1    = (const float*)d_in[5];
  const float* q1    = (const float*)d_in[6];
  const float* k1    = (const float*)d_in[7];
  const float* b1    = (const float*)d_in[8];
  const float* w2    = (const float*)d_in[9];
  const float* q2    = (const float*)d_in[10];
  const float* k2    = (const float*)d_in[11];
  const float* b2    = (const float*)d_in[12];
  const float* lw    = (const float*)d_in[13];
  const float* lb    = (const float*)d_in[14];

  int N = in_sizes[3];
  int M = in_sizes[0] / N;
  int E = in_sizes[2];
  int R = in_sizes[5] / (128 * 128);
  int NB = N * R;
  const int* esrc = eidx;
  const int* edst = eidx + E;

  char* p = (char*)d_ws;
  auto carve = [&](size_t b) -> void* {
    void* q = (void*)p; p += (b + 255) & ~(size_t)255; return q;
  };
  float* x_a  = (float*)carve((size_t)N * D * 4);
  float* x_b  = (float*)carve((size_t)N * D * 4);
  float* wq1  = (float*)carve((size_t)R * D * 4);
  float* wk1  = (float*)carve((size_t)R * D * 4);
  float* wq2  = (float*)carve((size_t)R * D * 4);
  float* wk2  = (float*)carve((size_t)R * D * 4);
  float* aT   = (float*)carve((size_t)N * R * 4);
  float* bT   = (float*)carve((size_t)N * R * 4);
  int*   rp   = (int*)carve((size_t)(NB + 1) * 4);
  int*   cur  = (int*)carve((size_t)NB * 4);
  int*   pack = (int*)carve((size_t)E * 4);
  float* alp  = (float*)carve((size_t)E * 4);
  unsigned short* wbf1 = (unsigned short*)carve((size_t)R * 128 * 128 * 2);
  unsigned short* wbf2 = (unsigned short*)carve((size_t)R * 128 * 128 * 2);
  unsigned short* lwbf = (unsigned short*)carve((size_t)128 * 128 * 2);
  int* bsum = (int*)carve((size_t)4096 * 4);
  int* boff = (int*)carve((size_t)4096 * 4);
  if ((size_t)(p - (char*)d_ws) > ws_size) return;  // base ws too small: fail visibly
  unsigned short* xw = (unsigned short*)carve((size_t)N * R * 128 * 2);
  bool use_xw = ((size_t)(p - (char*)d_ws) <= ws_size);

  hipMemsetAsync(cur, 0, (size_t)NB * 4, stream);
  hipMemsetAsync(d_out, 0, (size_t)out_size * 4, stream);

  int eg = (E + 255) / 256;
  int nblk = (NB + 1023) / 1024;
  k_count   <<<eg, 256, 0, stream>>>(edst, etyp, cur, E, R);
  k_scan_blk<<<nblk, 256, 0, stream>>>(cur, bsum, NB);
  k_scan_top<<<1, 1024, 0, stream>>>(bsum, boff, rp, nblk, NB);
  k_scan_fin<<<nblk, 256, 0, stream>>>(cur, boff, rp, NB);
  k_scatter <<<eg, 256, 0, stream>>>(esrc, edst, etyp, cur, pack, E, R);

  k_wqk<<<(R * D + 255) / 256, 256, 0, stream>>>(w1, q1, k1, wq1, wk1, R * D);
  k_wqk<<<(R * D + 255) / 256, 256, 0, stream>>>(w2, q2, k2, wq2, wk2, R * D);
  int wtot = R * 128 * 128;
  k_wtr<<<(wtot + 255) / 256, 256, 0, stream>>>(w1, wbf1, wtot);
  k_wtr<<<(wtot + 255) / 256, 256, 0, stream>>>(w2, wbf2, wtot);
  k_cvt<<<(128 * 128 + 255) / 256, 256, 0, stream>>>(lw, lwbf, 128 * 128);

  int ng4 = (N + 3) / 4;
  int ntile = (N + 63) / 64;
  int nwg = ntile * 4;   // 2 relations per block (R==8 -> 4 r-pairs)
  k_pool<<<ng4, 256, 0, stream>>>(xpad, emb, x_a, N, M);

  // layer 1
  k_ab   <<<ng4, 256, 0, stream>>>(x_a, wq1, wk1, aT, bT, N, R);
  k_alpha<<<ng4, 256, 0, stream>>>(rp, pack, aT, bT, alp, N, R);
  if (use_xw){
    k_xw  <<<nwg, 256, 0, stream>>>(x_a, wbf1, xw, N, R, nwg);
    k_aggX<<<ng4, 256, 0, stream>>>(xw, rp, pack, alp, b1, x_b, N, R);
  } else {
    k_agg <<<ntile, 256, 0, stream>>>(x_a, wbf1, b1, rp, pack, alp, x_b, N, R);
  }

  // layer 2
  k_ab   <<<ng4, 256, 0, stream>>>(x_b, wq2, wk2, aT, bT, N, R);
  k_alpha<<<ng4, 256, 0, stream>>>(rp, pack, aT, bT, alp, N, R);
  if (use_xw){
    k_xw  <<<nwg, 256, 0, stream>>>(x_b, wbf2, xw, N, R, nwg);
    k_aggX<<<ng4, 256, 0, stream>>>(xw, rp, pack, alp, b2, x_a, N, R);
  } else {
    k_agg <<<ntile, 256, 0, stream>>>(x_b, wbf2, b2, rp, pack, alp, x_a, N, R);
  }

  // final linear + graph segment-sum
  k_final<<<ntile, 256, 0, stream>>>(x_a, lwbf, lb, batch, (float*)d_out, N);
}